// Round 9
// baseline (510.933 us; speedup 1.0000x reference)
//
#include <hip/hip_runtime.h>

// ---------------------------------------------------------------------------
// GraphEncoder round 9:
//  - wgemm: 64 rows/WAVE (4 A-frag groups) -> 16 MFMA per 4 LDS b128 reads
//    (was 8 per 4): halves LDS-pipe pressure per FLOP. 128-thr 2-wave blocks.
//  - 16 dispatches (was 19): scanB folded into scanC; convert_all fuses
//    x̂-convert + 5 weight transposes + dummy-row zeroing.
//  - aggregation untouched (measured floor: ~58.5us, ~3.7 TB/s random gather).
// ---------------------------------------------------------------------------

typedef __attribute__((ext_vector_type(8))) short short8;
typedef __attribute__((ext_vector_type(4))) float f32x4;

__device__ __forceinline__ float bf2f(unsigned short s) {
    union { unsigned u; float f; } v;
    v.u = ((unsigned)s) << 16;
    return v.f;
}
__device__ __forceinline__ unsigned short f2bf(float f) {
    union { float f; unsigned u; } v;
    v.f = f;
    unsigned r = (v.u + 0x7FFFu + ((v.u >> 16) & 1u)) >> 16;
    return (unsigned short)r;
}

// ---------------------------- CSR build ------------------------------------

__global__ void count_kernel(const int* __restrict__ dst, int E, int* __restrict__ cnt) {
    int e = blockIdx.x * blockDim.x + threadIdx.x;
    if (e < E) atomicAdd(&cnt[dst[e]], 1);
}

// Phase A: per-block sums of cnt (512/block) + dinv.
__global__ void scanA(const int* __restrict__ cnt, int n, int* __restrict__ bsum,
                      float* __restrict__ dinv) {
    int tid = threadIdx.x, lane = tid & 63, w = tid >> 6;
    int i = blockIdx.x * 512 + tid;
    int v = (i < n) ? cnt[i] : 0;
    if (i < n) dinv[i] = rsqrtf((float)v + 1.0f);
    int s = v;
    #pragma unroll
    for (int off = 1; off < 64; off <<= 1) s += __shfl_xor(s, off);
    __shared__ int ws[8];
    if (lane == 0) ws[w] = s;
    __syncthreads();
    if (tid == 0) {
        int t = 0;
        #pragma unroll
        for (int j = 0; j < 8; j++) t += ws[j];
        bsum[blockIdx.x] = t;
    }
}

// Phase C: block offset computed from RAW bsum (wave sum over b < bid) +
// block-local exclusive scan -> row_ptr. Block 0 writes row_ptr[n] = E.
__global__ void scanC(const int* __restrict__ cnt, int n, const int* __restrict__ bsum,
                      int E, int* __restrict__ row_ptr) {
    int tid = threadIdx.x, lane = tid & 63, w = tid >> 6;
    int i = blockIdx.x * 512 + tid;
    __shared__ int s_boff;
    if (tid < 64) {
        int acc = 0;
        for (int b = tid; b < blockIdx.x; b += 64) acc += bsum[b];
        #pragma unroll
        for (int off = 1; off < 64; off <<= 1) acc += __shfl_xor(acc, off);
        if (tid == 0) s_boff = acc;
    }
    int v = (i < n) ? cnt[i] : 0;
    int incl = v;
    #pragma unroll
    for (int off = 1; off < 64; off <<= 1) {
        int t = __shfl_up(incl, off);
        if (lane >= off) incl += t;
    }
    __shared__ int ws[8];
    if (lane == 63) ws[w] = incl;
    __syncthreads();
    int woff = 0;
    for (int j = 0; j < w; j++) woff += ws[j];
    if (i < n) row_ptr[i] = s_boff + woff + incl - v;
    if (blockIdx.x == 0 && tid == 0) row_ptr[n] = E;
}

__global__ void scatter_kernel(const int* __restrict__ src, const int* __restrict__ dst, int E,
                               const int* __restrict__ row_ptr, int* __restrict__ fill,
                               int* __restrict__ csr) {
    int e = blockIdx.x * blockDim.x + threadIdx.x;
    if (e < E) {
        int d = dst[e];
        int pos = atomicAdd(&fill[d], 1);
        csr[row_ptr[d] + pos] = src[e];
    }
}

// ---------------------------- conversions (fused) --------------------------
// [0, n4):            x̂ = dinv*x, float4 granular (F_IN=128 -> row = i>>5)
// [n4, n4+tot):       weight transpose W[K,N] fp32 -> Wt[N,K] bf16
// [n4+tot, +640):     zero dummy rows of xh (128), hh1 (256), hh2 (256)

__global__ void convert_all(const float* __restrict__ x, const float* __restrict__ dinv,
                            unsigned short* __restrict__ xh, int n4,
                            const float* __restrict__ W1, const float* __restrict__ W2,
                            const float* __restrict__ W3, const float* __restrict__ P1,
                            const float* __restrict__ P2,
                            unsigned short* __restrict__ Wt1, unsigned short* __restrict__ Wt2,
                            unsigned short* __restrict__ Wt3, unsigned short* __restrict__ Pt1,
                            unsigned short* __restrict__ Pt2,
                            int F_IN, int H, int D,
                            unsigned short* __restrict__ zx,
                            unsigned short* __restrict__ z1,
                            unsigned short* __restrict__ z2) {
    int idx = blockIdx.x * blockDim.x + threadIdx.x;
    if (idx < n4) {
        float di = dinv[idx >> 5];
        float4 v = ((const float4*)x)[idx];
        ushort4 o;
        o.x = f2bf(di * v.x); o.y = f2bf(di * v.y);
        o.z = f2bf(di * v.z); o.w = f2bf(di * v.w);
        ((ushort4*)xh)[idx] = o;
        return;
    }
    int t = idx - n4;
    int n1 = F_IN * H, n2 = H * H, n5 = H * D;
    const float* W; unsigned short* O; int N;
    if (t < n1)              { W = W1; O = Wt1; N = H; }
    else if ((t -= n1) < n2) { W = W2; O = Wt2; N = H; }
    else if ((t -= n2) < n2) { W = W3; O = Wt3; N = H; }
    else if ((t -= n2) < n2) { W = P1; O = Pt1; N = H; }
    else if ((t -= n2) < n5) { W = P2; O = Pt2; N = D; }
    else {
        t -= n5;
        if (t < 128) zx[t] = 0;
        else if (t < 384) z1[t - 128] = 0;
        else if (t < 640) z2[t - 384] = 0;
        return;
    }
    int k = t / N, n = t - k * N;
    int K = (W == W1) ? F_IN : H;
    O[(size_t)n * K + k] = f2bf(W[t]);
}

// ---------------------------- aggregation (pure sum) -----------------------
// t[node] = ĥ[node] + sum_e ĥ[src_e]; zeroed dummy row `zrow` pads tails.

__launch_bounds__(256)
__global__ void aggregate256(const unsigned short* __restrict__ h,
                             const int* __restrict__ row_ptr,
                             const int* __restrict__ csr,
                             unsigned short* __restrict__ out, int n, int zrow) {
    int node = blockIdx.x * 4 + (threadIdx.x >> 6);
    int lane = threadIdx.x & 63;
    if (node >= n) return;
    int half = lane >> 5;
    int cl = lane & 31;
    float acc[8] = {0, 0, 0, 0, 0, 0, 0, 0};
    if (half == 0) {
        short8 sv = *(const short8*)(h + (size_t)node * 256 + cl * 8);
        #pragma unroll
        for (int c = 0; c < 8; c++) acc[c] = bf2f((unsigned short)sv[c]);
    }
    int beg = row_ptr[node], end = row_ptr[node + 1];
    for (int base = beg; base < end; base += 64) {
        int k = base + lane;
        int mi = (k < end) ? csr[k] : zrow;
        int cnt = min(64, end - base);
        for (int j = 0; j < cnt; j += 16) {
            int idx[8]; short8 vv[8];
            #pragma unroll
            for (int u = 0; u < 8; u++) idx[u] = __shfl(mi, j + 2 * u + half);
            #pragma unroll
            for (int u = 0; u < 8; u++) vv[u] = *(const short8*)(h + (size_t)idx[u] * 256 + cl * 8);
            #pragma unroll
            for (int u = 0; u < 8; u++)
                #pragma unroll
                for (int c = 0; c < 8; c++) acc[c] += bf2f((unsigned short)vv[u][c]);
        }
    }
    #pragma unroll
    for (int c = 0; c < 8; c++) acc[c] += __shfl_xor(acc[c], 32);
    if (half == 0) {
        short8 o;
        #pragma unroll
        for (int c = 0; c < 8; c++) o[c] = (short)f2bf(acc[c]);
        *(short8*)(out + (size_t)node * 256 + cl * 8) = o;
    }
}

__launch_bounds__(256)
__global__ void aggregate128(const unsigned short* __restrict__ h,
                             const int* __restrict__ row_ptr,
                             const int* __restrict__ csr,
                             unsigned short* __restrict__ out, int n, int zrow) {
    int node = blockIdx.x * 4 + (threadIdx.x >> 6);
    int lane = threadIdx.x & 63;
    if (node >= n) return;
    int qtr = lane >> 4;
    int cl = lane & 15;
    float acc[8] = {0, 0, 0, 0, 0, 0, 0, 0};
    if (qtr == 0) {
        short8 sv = *(const short8*)(h + (size_t)node * 128 + cl * 8);
        #pragma unroll
        for (int c = 0; c < 8; c++) acc[c] = bf2f((unsigned short)sv[c]);
    }
    int beg = row_ptr[node], end = row_ptr[node + 1];
    for (int base = beg; base < end; base += 64) {
        int k = base + lane;
        int mi = (k < end) ? csr[k] : zrow;
        int cnt = min(64, end - base);
        for (int j = 0; j < cnt; j += 32) {
            int idx[8]; short8 vv[8];
            #pragma unroll
            for (int u = 0; u < 8; u++) idx[u] = __shfl(mi, j + 4 * u + qtr);
            #pragma unroll
            for (int u = 0; u < 8; u++) vv[u] = *(const short8*)(h + (size_t)idx[u] * 128 + cl * 8);
            #pragma unroll
            for (int u = 0; u < 8; u++)
                #pragma unroll
                for (int c = 0; c < 8; c++) acc[c] += bf2f((unsigned short)vv[u][c]);
        }
    }
    #pragma unroll
    for (int c = 0; c < 8; c++) {
        acc[c] += __shfl_xor(acc[c], 16);
        acc[c] += __shfl_xor(acc[c], 32);
    }
    if (qtr == 0) {
        short8 o;
        #pragma unroll
        for (int c = 0; c < 8; c++) o[c] = (short)f2bf(acc[c]);
        *(short8*)(out + (size_t)node * 128 + cl * 8) = o;
    }
}

// ---------------------------- wgemm ----------------------------------------
// C = epi(A[M,K] @ Bt[N,K]^T). 128-thread blocks = 2 waves x 64 rows.
// A frags in registers (4 groups of 16 rows per wave); per 64-col tile B is
// staged to LDS; 16 MFMA per 4 ds_read_b128 (1:4).
// SCALE: 0 plain; 1: v=relu(di*acc+b)[+res/di], store di*v; 2: ...store v.

template<int K, int RELU, int RES, int OUTF32, int SCALE>
__launch_bounds__(128)
__global__ void wgemm(const unsigned short* __restrict__ A,
                      const unsigned short* __restrict__ Bt,
                      const float* __restrict__ bias,
                      const unsigned short* __restrict__ residual,
                      const float* __restrict__ dinv,
                      void* __restrict__ Cout,
                      int M, int N, int ntiles) {
    constexpr int KK = K / 32;
    constexpr int S = K + 8;
    constexpr int CPR = K / 8;
    __shared__ unsigned short Bs[64 * S];

    int tid = threadIdx.x;
    int wave = tid >> 6, lane = tid & 63;
    int r = lane & 15, q = lane >> 4;
    int mr = blockIdx.y * 128 + wave * 64;
    int nbase = blockIdx.x * ntiles * 64;

    short8 a[4][KK];
    #pragma unroll
    for (int mi = 0; mi < 4; mi++) {
        int arow = mr + mi * 16 + r;
        bool ok = arow < M;
        const unsigned short* ap = A + (size_t)(ok ? arow : 0) * K;
        #pragma unroll
        for (int kk = 0; kk < KK; kk++) {
            short8 v = *(const short8*)(ap + kk * 32 + q * 8);
            if (!ok) v = (short8){0, 0, 0, 0, 0, 0, 0, 0};
            a[mi][kk] = v;
        }
    }

    for (int t = 0; t < ntiles; t++) {
        int n0 = nbase + t * 64;
        if (t > 0) __syncthreads();
        #pragma unroll
        for (int pass = 0; pass < 64 * CPR / 128; pass++) {
            int f = pass * 128 + tid;
            int row = f / CPR, ch = f % CPR;
            *(short8*)&Bs[row * S + ch * 8] =
                *(const short8*)(Bt + (size_t)(n0 + row) * K + ch * 8);
        }
        __syncthreads();

        f32x4 acc[4][4];
        #pragma unroll
        for (int mi = 0; mi < 4; mi++)
            #pragma unroll
            for (int j = 0; j < 4; j++) acc[mi][j] = (f32x4){0.f, 0.f, 0.f, 0.f};

        #pragma unroll
        for (int kk = 0; kk < KK; kk++) {
            short8 b[4];
            #pragma unroll
            for (int j = 0; j < 4; j++)
                b[j] = *(short8*)&Bs[(j * 16 + r) * S + kk * 32 + q * 8];
            #pragma unroll
            for (int mi = 0; mi < 4; mi++)
                #pragma unroll
                for (int j = 0; j < 4; j++)
                    acc[mi][j] = __builtin_amdgcn_mfma_f32_16x16x32_bf16(a[mi][kk], b[j], acc[mi][j], 0, 0, 0);
        }

        float bb[4];
        #pragma unroll
        for (int j = 0; j < 4; j++) bb[j] = bias[n0 + j * 16 + r];

        #pragma unroll
        for (int mi = 0; mi < 4; mi++) {
            #pragma unroll
            for (int p = 0; p < 4; p++) {
                int row = mr + mi * 16 + q * 4 + p;
                if (row < M) {
                    float di = 1.f, rdi = 1.f;
                    if (SCALE) { di = dinv[row]; if (RES) rdi = 1.f / di; }
                    #pragma unroll
                    for (int j = 0; j < 4; j++) {
                        int col = n0 + j * 16 + r;
                        float v = (SCALE ? di * acc[mi][j][p] : acc[mi][j][p]) + bb[j];
                        if (RELU) v = fmaxf(v, 0.f);
                        if (RES) v += bf2f(residual[(size_t)row * N + col]) * rdi;
                        if (SCALE == 1) v *= di;
                        if (OUTF32) ((float*)Cout)[(size_t)row * N + col] = v;
                        else ((unsigned short*)Cout)[(size_t)row * N + col] = f2bf(v);
                    }
                }
            }
        }
    }
}

// ---------------------------- pool / LN ------------------------------------

__launch_bounds__(256)
__global__ void pool_kernel(const unsigned short* __restrict__ h, const int* __restrict__ batch,
                            unsigned short* __restrict__ g0, int n, int G) {
    int g = blockIdx.x * 4 + (threadIdx.x >> 6);
    int lane = threadIdx.x & 63;
    if (g >= G) return;
    int lo = 0, hi = 0;
    if (lane == 0) {
        int a = 0, b = n;
        while (a < b) { int m = (a + b) >> 1; if (batch[m] < g) a = m + 1; else b = m; }
        lo = a;
        int a2 = a, b2 = n;
        while (a2 < b2) { int m = (a2 + b2) >> 1; if (batch[m] < g + 1) a2 = m + 1; else b2 = m; }
        hi = a2;
    }
    lo = __shfl(lo, 0); hi = __shfl(hi, 0);
    float a0 = 0.f, a1 = 0.f, a2 = 0.f, a3 = 0.f;
    for (int i = lo; i < hi; i++) {
        ushort4 v = *(const ushort4*)(h + (size_t)i * 256 + lane * 4);
        a0 += bf2f(v.x); a1 += bf2f(v.y); a2 += bf2f(v.z); a3 += bf2f(v.w);
    }
    float inv = 1.0f / fmaxf((float)(hi - lo), 1.0f);
    ushort4 o;
    o.x = f2bf(a0 * inv); o.y = f2bf(a1 * inv); o.z = f2bf(a2 * inv); o.w = f2bf(a3 * inv);
    *(ushort4*)(g0 + (size_t)g * 256 + lane * 4) = o;
}

__launch_bounds__(256)
__global__ void ln_kernel(const float* __restrict__ g2, const float* __restrict__ gamma,
                          const float* __restrict__ beta, float* __restrict__ out, int rows) {
    int row = blockIdx.x * 4 + (threadIdx.x >> 6);
    int lane = threadIdx.x & 63;
    if (row >= rows) return;
    const float* r = g2 + (size_t)row * 768;
    float v[12];
    float s = 0.f, s2 = 0.f;
    #pragma unroll
    for (int j = 0; j < 12; j++) {
        v[j] = r[lane + 64 * j];
        s += v[j];
        s2 += v[j] * v[j];
    }
    #pragma unroll
    for (int off = 32; off > 0; off >>= 1) {
        s += __shfl_down(s, off);
        s2 += __shfl_down(s2, off);
    }
    s = __shfl(s, 0);
    s2 = __shfl(s2, 0);
    float mu = s * (1.0f / 768.0f);
    float var = s2 * (1.0f / 768.0f) - mu * mu;
    float inv = rsqrtf(var + 1e-5f);
    #pragma unroll
    for (int j = 0; j < 12; j++) {
        int c = lane + 64 * j;
        out[(size_t)row * 768 + c] = (v[j] - mu) * inv * gamma[c] + beta[c];
    }
}

// ---------------------------------------------------------------------------

extern "C" void kernel_launch(void* const* d_in, const int* in_sizes, int n_in,
                              void* d_out, int out_size, void* d_ws, size_t ws_size,
                              hipStream_t stream) {
    const float* x    = (const float*)d_in[0];
    const int* eidx   = (const int*)d_in[1];
    const int* batch  = (const int*)d_in[2];
    const float* W1   = (const float*)d_in[3];
    const float* b1   = (const float*)d_in[4];
    const float* W2   = (const float*)d_in[5];
    const float* b2   = (const float*)d_in[6];
    const float* W3   = (const float*)d_in[7];
    const float* b3   = (const float*)d_in[8];
    const float* P1   = (const float*)d_in[9];
    const float* pb1  = (const float*)d_in[10];
    const float* P2   = (const float*)d_in[11];
    const float* pb2  = (const float*)d_in[12];
    const float* ln_g = (const float*)d_in[13];
    const float* ln_b = (const float*)d_in[14];
    float* out = (float*)d_out;

    const int N = in_sizes[2];            // 50000
    const int E = in_sizes[1] / 2;        // 800000
    const int F_IN = in_sizes[0] / N;     // 128
    const int H = in_sizes[4];            // 256
    const int D = in_sizes[12];           // 768
    const int G = out_size / D;           // 1024
    const int NPAD = (N + 127) & ~127;
    const int NB = (N + 511) / 512;       // scan blocks (<=128)

    const int* src = eidx;
    const int* dst = eidx + E;

    char* ws = (char*)d_ws;
    size_t off = 0;
    auto alloc = [&](size_t bytes) -> char* {
        char* p = ws + off;
        off = (off + bytes + 255) & ~(size_t)255;
        return p;
    };
    int*   cnt      = (int*)alloc((size_t)NPAD * 4);   // cnt & fill contiguous -> one memset
    int*   fill     = (int*)alloc((size_t)NPAD * 4);
    float* dinv     = (float*)alloc((size_t)NPAD * 4);
    int*   row_ptr  = (int*)alloc((size_t)(N + 1) * 4);
    int*   bsum     = (int*)alloc(128 * 4);
    int*   csr      = (int*)alloc((size_t)E * 4);
    unsigned short* xh  = (unsigned short*)alloc((size_t)(N + 1) * F_IN * 2);  // x̂, +dummy row
    unsigned short* Wt1 = (unsigned short*)alloc((size_t)F_IN * H * 2);
    unsigned short* Wt2 = (unsigned short*)alloc((size_t)H * H * 2);
    unsigned short* Wt3 = (unsigned short*)alloc((size_t)H * H * 2);
    unsigned short* Pt1 = (unsigned short*)alloc((size_t)H * H * 2);
    unsigned short* Pt2 = (unsigned short*)alloc((size_t)H * D * 2);
    unsigned short* t1  = (unsigned short*)alloc((size_t)N * F_IN * 2);        // Σ x̂
    unsigned short* tA  = (unsigned short*)alloc((size_t)N * H * 2);           // Σ ĥ (shared)
    unsigned short* hh1 = (unsigned short*)alloc((size_t)(N + 1) * H * 2);     // ĥ1, +dummy
    unsigned short* hh2 = (unsigned short*)alloc((size_t)(N + 1) * H * 2);     // ĥ2, +dummy
    unsigned short* h3  = (unsigned short*)alloc((size_t)N * H * 2);
    unsigned short* g0b = (unsigned short*)alloc((size_t)G * H * 2);
    unsigned short* g1b = (unsigned short*)alloc((size_t)G * H * 2);
    float* g2 = (float*)alloc((size_t)G * D * 4);
    (void)ws_size; (void)n_in;

    // --- CSR build -----------------------------------------------------------
    hipMemsetAsync(cnt, 0, (size_t)2 * NPAD * 4, stream);
    count_kernel<<<(E + 255) / 256, 256, 0, stream>>>(dst, E, cnt);
    scanA<<<NB, 512, 0, stream>>>(cnt, N, bsum, dinv);
    scanC<<<NB, 512, 0, stream>>>(cnt, N, bsum, E, row_ptr);
    scatter_kernel<<<(E + 255) / 256, 256, 0, stream>>>(src, dst, E, row_ptr, fill, csr);

    // --- conversions (one launch) -------------------------------------------
    {
        int n4 = N * F_IN / 4;
        int tot = F_IN * H + 3 * H * H + H * D;
        int total = n4 + tot + 640;
        convert_all<<<(total + 255) / 256, 256, 0, stream>>>(
            x, dinv, xh, n4, W1, W2, W3, P1, P2, Wt1, Wt2, Wt3, Pt1, Pt2, F_IN, H, D,
            xh + (size_t)N * F_IN, hh1 + (size_t)N * H, hh2 + (size_t)N * H);
    }

    // --- GCN layers (aggregate-first, ĥ-space) ------------------------------
    int agg_grid = (N + 3) / 4;
    int mtiles = (N + 127) / 128;

    // layer 1: t1 = x̂[i] + Σ x̂[src]; ĥ1 = di*relu(di*(t1 W1) + b1)
    aggregate128<<<agg_grid, 256, 0, stream>>>(xh, row_ptr, csr, t1, N, N);
    wgemm<128, 1, 0, 0, 1><<<dim3(2, mtiles), 128, 0, stream>>>(t1, Wt1, b1, nullptr, dinv, hh1, N, H, 2);

    // layer 2: t2 = ĥ1[i] + Σ ĥ1[src]; ĥ2 = di*(relu(di*(t2 W2)+b2) + ĥ1/di)
    aggregate256<<<agg_grid, 256, 0, stream>>>(hh1, row_ptr, csr, tA, N, N);
    wgemm<256, 1, 1, 0, 1><<<dim3(2, mtiles), 128, 0, stream>>>(tA, Wt2, b2, hh1, dinv, hh2, N, H, 2);

    // layer 3: t3 = ĥ2[i] + Σ ĥ2[src]; h3 = relu(di*(t3 W3)+b3) + ĥ2/di
    aggregate256<<<agg_grid, 256, 0, stream>>>(hh2, row_ptr, csr, tA, N, N);
    wgemm<256, 1, 1, 0, 2><<<dim3(2, mtiles), 128, 0, stream>>>(tA, Wt3, b3, hh2, dinv, h3, N, H, 2);

    // --- pool + MLP + LN -----------------------------------------------------
    pool_kernel<<<(G + 3) / 4, 256, 0, stream>>>(h3, batch, g0b, N, G);
    wgemm<256, 1, 0, 0, 0><<<dim3(4, G / 128), 128, 0, stream>>>(g0b, Pt1, pb1, nullptr, nullptr, g1b, G, H, 1);
    wgemm<256, 0, 0, 1, 0><<<dim3(12, G / 128), 128, 0, stream>>>(g1b, Pt2, pb2, nullptr, nullptr, g2, G, D, 1);
    ln_kernel<<<G / 4, 256, 0, stream>>>(g2, ln_g, ln_b, out, G);
}

// Round 10
// 447.877 us; speedup vs baseline: 1.1408x; 1.1408x over previous
//
#include <hip/hip_runtime.h>

// ---------------------------------------------------------------------------
// GraphEncoder round 10:
//  - wgemm back to R8 shape (256 thr, 4 waves x 32 rows, grid(2,391), 12+
//    waves/CU) -- R9's 64-row waves collapsed occupancy to 2.5 waves/CU.
//  - NEW: LDS-transpose epilogue. acc -> LDS (reuses B buffer) -> per-thread
//    row-major readback -> coalesced 64B vectorized stores + vectorized
//    residual loads (was 2B scattered).
//  - aggregation / CSR / conversions unchanged (measured floor).
// ---------------------------------------------------------------------------

typedef __attribute__((ext_vector_type(8))) short short8;
typedef __attribute__((ext_vector_type(4))) float f32x4;

__device__ __forceinline__ float bf2f(unsigned short s) {
    union { unsigned u; float f; } v;
    v.u = ((unsigned)s) << 16;
    return v.f;
}
__device__ __forceinline__ unsigned short f2bf(float f) {
    union { float f; unsigned u; } v;
    v.f = f;
    unsigned r = (v.u + 0x7FFFu + ((v.u >> 16) & 1u)) >> 16;
    return (unsigned short)r;
}

// ---------------------------- CSR build ------------------------------------

__global__ void count_kernel(const int* __restrict__ dst, int E, int* __restrict__ cnt) {
    int e = blockIdx.x * blockDim.x + threadIdx.x;
    if (e < E) atomicAdd(&cnt[dst[e]], 1);
}

__global__ void scanA(const int* __restrict__ cnt, int n, int* __restrict__ bsum,
                      float* __restrict__ dinv) {
    int tid = threadIdx.x, lane = tid & 63, w = tid >> 6;
    int i = blockIdx.x * 512 + tid;
    int v = (i < n) ? cnt[i] : 0;
    if (i < n) dinv[i] = rsqrtf((float)v + 1.0f);
    int s = v;
    #pragma unroll
    for (int off = 1; off < 64; off <<= 1) s += __shfl_xor(s, off);
    __shared__ int ws[8];
    if (lane == 0) ws[w] = s;
    __syncthreads();
    if (tid == 0) {
        int t = 0;
        #pragma unroll
        for (int j = 0; j < 8; j++) t += ws[j];
        bsum[blockIdx.x] = t;
    }
}

__global__ void scanC(const int* __restrict__ cnt, int n, const int* __restrict__ bsum,
                      int E, int* __restrict__ row_ptr) {
    int tid = threadIdx.x, lane = tid & 63, w = tid >> 6;
    int i = blockIdx.x * 512 + tid;
    __shared__ int s_boff;
    if (tid < 64) {
        int acc = 0;
        for (int b = tid; b < blockIdx.x; b += 64) acc += bsum[b];
        #pragma unroll
        for (int off = 1; off < 64; off <<= 1) acc += __shfl_xor(acc, off);
        if (tid == 0) s_boff = acc;
    }
    int v = (i < n) ? cnt[i] : 0;
    int incl = v;
    #pragma unroll
    for (int off = 1; off < 64; off <<= 1) {
        int t = __shfl_up(incl, off);
        if (lane >= off) incl += t;
    }
    __shared__ int ws[8];
    if (lane == 63) ws[w] = incl;
    __syncthreads();
    int woff = 0;
    for (int j = 0; j < w; j++) woff += ws[j];
    if (i < n) row_ptr[i] = s_boff + woff + incl - v;
    if (blockIdx.x == 0 && tid == 0) row_ptr[n] = E;
}

__global__ void scatter_kernel(const int* __restrict__ src, const int* __restrict__ dst, int E,
                               const int* __restrict__ row_ptr, int* __restrict__ fill,
                               int* __restrict__ csr) {
    int e = blockIdx.x * blockDim.x + threadIdx.x;
    if (e < E) {
        int d = dst[e];
        int pos = atomicAdd(&fill[d], 1);
        csr[row_ptr[d] + pos] = src[e];
    }
}

// ---------------------------- conversions (fused) --------------------------

__global__ void convert_all(const float* __restrict__ x, const float* __restrict__ dinv,
                            unsigned short* __restrict__ xh, int n4,
                            const float* __restrict__ W1, const float* __restrict__ W2,
                            const float* __restrict__ W3, const float* __restrict__ P1,
                            const float* __restrict__ P2,
                            unsigned short* __restrict__ Wt1, unsigned short* __restrict__ Wt2,
                            unsigned short* __restrict__ Wt3, unsigned short* __restrict__ Pt1,
                            unsigned short* __restrict__ Pt2,
                            int F_IN, int H, int D,
                            unsigned short* __restrict__ zx,
                            unsigned short* __restrict__ z1,
                            unsigned short* __restrict__ z2) {
    int idx = blockIdx.x * blockDim.x + threadIdx.x;
    if (idx < n4) {
        float di = dinv[idx >> 5];
        float4 v = ((const float4*)x)[idx];
        ushort4 o;
        o.x = f2bf(di * v.x); o.y = f2bf(di * v.y);
        o.z = f2bf(di * v.z); o.w = f2bf(di * v.w);
        ((ushort4*)xh)[idx] = o;
        return;
    }
    int t = idx - n4;
    int n1 = F_IN * H, n2 = H * H, n5 = H * D;
    const float* W; unsigned short* O; int N;
    if (t < n1)              { W = W1; O = Wt1; N = H; }
    else if ((t -= n1) < n2) { W = W2; O = Wt2; N = H; }
    else if ((t -= n2) < n2) { W = W3; O = Wt3; N = H; }
    else if ((t -= n2) < n2) { W = P1; O = Pt1; N = H; }
    else if ((t -= n2) < n5) { W = P2; O = Pt2; N = D; }
    else {
        t -= n5;
        if (t < 128) zx[t] = 0;
        else if (t < 384) z1[t - 128] = 0;
        else if (t < 640) z2[t - 384] = 0;
        return;
    }
    int k = t / N, n = t - k * N;
    int K = (W == W1) ? F_IN : H;
    O[(size_t)n * K + k] = f2bf(W[t]);
}

// ---------------------------- aggregation (pure sum) -----------------------

__launch_bounds__(256)
__global__ void aggregate256(const unsigned short* __restrict__ h,
                             const int* __restrict__ row_ptr,
                             const int* __restrict__ csr,
                             unsigned short* __restrict__ out, int n, int zrow) {
    int node = blockIdx.x * 4 + (threadIdx.x >> 6);
    int lane = threadIdx.x & 63;
    if (node >= n) return;
    int half = lane >> 5;
    int cl = lane & 31;
    float acc[8] = {0, 0, 0, 0, 0, 0, 0, 0};
    if (half == 0) {
        short8 sv = *(const short8*)(h + (size_t)node * 256 + cl * 8);
        #pragma unroll
        for (int c = 0; c < 8; c++) acc[c] = bf2f((unsigned short)sv[c]);
    }
    int beg = row_ptr[node], end = row_ptr[node + 1];
    for (int base = beg; base < end; base += 64) {
        int k = base + lane;
        int mi = (k < end) ? csr[k] : zrow;
        int cnt = min(64, end - base);
        for (int j = 0; j < cnt; j += 16) {
            int idx[8]; short8 vv[8];
            #pragma unroll
            for (int u = 0; u < 8; u++) idx[u] = __shfl(mi, j + 2 * u + half);
            #pragma unroll
            for (int u = 0; u < 8; u++) vv[u] = *(const short8*)(h + (size_t)idx[u] * 256 + cl * 8);
            #pragma unroll
            for (int u = 0; u < 8; u++)
                #pragma unroll
                for (int c = 0; c < 8; c++) acc[c] += bf2f((unsigned short)vv[u][c]);
        }
    }
    #pragma unroll
    for (int c = 0; c < 8; c++) acc[c] += __shfl_xor(acc[c], 32);
    if (half == 0) {
        short8 o;
        #pragma unroll
        for (int c = 0; c < 8; c++) o[c] = (short)f2bf(acc[c]);
        *(short8*)(out + (size_t)node * 256 + cl * 8) = o;
    }
}

__launch_bounds__(256)
__global__ void aggregate128(const unsigned short* __restrict__ h,
                             const int* __restrict__ row_ptr,
                             const int* __restrict__ csr,
                             unsigned short* __restrict__ out, int n, int zrow) {
    int node = blockIdx.x * 4 + (threadIdx.x >> 6);
    int lane = threadIdx.x & 63;
    if (node >= n) return;
    int qtr = lane >> 4;
    int cl = lane & 15;
    float acc[8] = {0, 0, 0, 0, 0, 0, 0, 0};
    if (qtr == 0) {
        short8 sv = *(const short8*)(h + (size_t)node * 128 + cl * 8);
        #pragma unroll
        for (int c = 0; c < 8; c++) acc[c] = bf2f((unsigned short)sv[c]);
    }
    int beg = row_ptr[node], end = row_ptr[node + 1];
    for (int base = beg; base < end; base += 64) {
        int k = base + lane;
        int mi = (k < end) ? csr[k] : zrow;
        int cnt = min(64, end - base);
        for (int j = 0; j < cnt; j += 32) {
            int idx[8]; short8 vv[8];
            #pragma unroll
            for (int u = 0; u < 8; u++) idx[u] = __shfl(mi, j + 4 * u + qtr);
            #pragma unroll
            for (int u = 0; u < 8; u++) vv[u] = *(const short8*)(h + (size_t)idx[u] * 128 + cl * 8);
            #pragma unroll
            for (int u = 0; u < 8; u++)
                #pragma unroll
                for (int c = 0; c < 8; c++) acc[c] += bf2f((unsigned short)vv[u][c]);
        }
    }
    #pragma unroll
    for (int c = 0; c < 8; c++) {
        acc[c] += __shfl_xor(acc[c], 16);
        acc[c] += __shfl_xor(acc[c], 32);
    }
    if (qtr == 0) {
        short8 o;
        #pragma unroll
        for (int c = 0; c < 8; c++) o[c] = (short)f2bf(acc[c]);
        *(short8*)(out + (size_t)node * 128 + cl * 8) = o;
    }
}

// ---------------------------- wgemm ----------------------------------------
// C = epi(A[M,K] @ Bt[N,K]^T). 256-thr blocks = 4 waves x 32 rows (128 rows).
// A frags in registers (read once); per 64-col tile B staged to LDS; after
// MFMA, acc goes through an LDS transpose so the epilogue does coalesced
// vectorized residual loads + stores (1 row x 32 cols per thread).
// SCALE: 0 plain; 1: v=relu(di*acc+b)[+res/di], store di*v; 2: ...store v.

template<int K, int RELU, int RES, int OUTF32, int SCALE>
__launch_bounds__(256)
__global__ void wgemm(const unsigned short* __restrict__ A,
                      const unsigned short* __restrict__ Bt,
                      const float* __restrict__ bias,
                      const unsigned short* __restrict__ residual,
                      const float* __restrict__ dinv,
                      void* __restrict__ Cout,
                      int M, int N, int ntiles) {
    constexpr int KK = K / 32;
    constexpr int S = K + 8;           // B-stage stride (shorts)
    constexpr int CS = 65;             // fp32 transpose stride (floats)
    constexpr int BSZ = 64 * S * 2;
    constexpr int CSZ = 128 * CS * 4;
    constexpr int SM = BSZ > CSZ ? BSZ : CSZ;
    __shared__ __align__(16) char smraw[SM];
    unsigned short* Bs = (unsigned short*)smraw;
    float* Cs = (float*)smraw;
    constexpr int CPR = K / 8;

    int tid = threadIdx.x;
    int wave = tid >> 6, lane = tid & 63;
    int r = lane & 15, q = lane >> 4;
    int mr = blockIdx.y * 128 + wave * 32;
    int nbase = blockIdx.x * ntiles * 64;

    short8 a[2][KK];
    #pragma unroll
    for (int mi = 0; mi < 2; mi++) {
        int arow = mr + mi * 16 + r;
        bool ok = arow < M;
        const unsigned short* ap = A + (size_t)(ok ? arow : 0) * K;
        #pragma unroll
        for (int kk = 0; kk < KK; kk++) {
            short8 v = *(const short8*)(ap + kk * 32 + q * 8);
            if (!ok) v = (short8){0, 0, 0, 0, 0, 0, 0, 0};
            a[mi][kk] = v;
        }
    }

    for (int t = 0; t < ntiles; t++) {
        int n0 = nbase + t * 64;
        if (t > 0) __syncthreads();   // previous tile's LDS reads complete
        #pragma unroll
        for (int pass = 0; pass < 64 * CPR / 256; pass++) {
            int f = pass * 256 + tid;
            int row = f / CPR, ch = f % CPR;
            *(short8*)&Bs[row * S + ch * 8] =
                *(const short8*)(Bt + (size_t)(n0 + row) * K + ch * 8);
        }
        __syncthreads();

        f32x4 acc[2][4];
        #pragma unroll
        for (int mi = 0; mi < 2; mi++)
            #pragma unroll
            for (int j = 0; j < 4; j++) acc[mi][j] = (f32x4){0.f, 0.f, 0.f, 0.f};

        #pragma unroll
        for (int kk = 0; kk < KK; kk++) {
            short8 b[4];
            #pragma unroll
            for (int j = 0; j < 4; j++)
                b[j] = *(short8*)&Bs[(j * 16 + r) * S + kk * 32 + q * 8];
            #pragma unroll
            for (int mi = 0; mi < 2; mi++)
                #pragma unroll
                for (int j = 0; j < 4; j++)
                    acc[mi][j] = __builtin_amdgcn_mfma_f32_16x16x32_bf16(a[mi][kk], b[j], acc[mi][j], 0, 0, 0);
        }

        // ---- LDS transpose epilogue ----
        __syncthreads();   // B reads done; Cs aliases Bs
        #pragma unroll
        for (int mi = 0; mi < 2; mi++)
            #pragma unroll
            for (int j = 0; j < 4; j++)
                #pragma unroll
                for (int p = 0; p < 4; p++)
                    Cs[(wave * 32 + mi * 16 + q * 4 + p) * CS + j * 16 + r] = acc[mi][j][p];
        __syncthreads();

        int row = tid >> 1;            // 0..127
        int halfc = (tid & 1) * 32;    // 0 or 32
        int grow = blockIdx.y * 128 + row;
        if (grow < M) {
            float vals[32];
            #pragma unroll
            for (int c = 0; c < 8; c++)
                *(f32x4*)&vals[c * 4] = *(f32x4*)&Cs[row * CS + halfc + c * 4];
            float di = 1.f, rdi = 1.f;
            if (SCALE) { di = dinv[grow]; if (RES) rdi = 1.f / di; }
            float bb[32];
            #pragma unroll
            for (int c = 0; c < 8; c++)
                *(f32x4*)&bb[c * 4] = *(const f32x4*)&bias[n0 + halfc + c * 4];
            short8 rv[4];
            if (RES) {
                #pragma unroll
                for (int c = 0; c < 4; c++)
                    rv[c] = *(const short8*)(residual + (size_t)grow * N + n0 + halfc + c * 8);
            }
            #pragma unroll
            for (int c = 0; c < 32; c++) {
                float v = (SCALE ? di * vals[c] : vals[c]) + bb[c];
                if (RELU) v = fmaxf(v, 0.f);
                if (RES) v += bf2f((unsigned short)rv[c / 8][c % 8]) * rdi;
                if (SCALE == 1) v *= di;
                vals[c] = v;
            }
            if (OUTF32) {
                float* cp = (float*)Cout + (size_t)grow * N + n0 + halfc;
                #pragma unroll
                for (int c = 0; c < 8; c++) *(f32x4*)&cp[c * 4] = *(f32x4*)&vals[c * 4];
            } else {
                unsigned short* cp = (unsigned short*)Cout + (size_t)grow * N + n0 + halfc;
                #pragma unroll
                for (int c = 0; c < 4; c++) {
                    short8 o;
                    #pragma unroll
                    for (int u = 0; u < 8; u++) o[u] = (short)f2bf(vals[c * 8 + u]);
                    *(short8*)&cp[c * 8] = o;
                }
            }
        }
    }
}

// ---------------------------- pool / LN ------------------------------------

__launch_bounds__(256)
__global__ void pool_kernel(const unsigned short* __restrict__ h, const int* __restrict__ batch,
                            unsigned short* __restrict__ g0, int n, int G) {
    int g = blockIdx.x * 4 + (threadIdx.x >> 6);
    int lane = threadIdx.x & 63;
    if (g >= G) return;
    int lo = 0, hi = 0;
    if (lane == 0) {
        int a = 0, b = n;
        while (a < b) { int m = (a + b) >> 1; if (batch[m] < g) a = m + 1; else b = m; }
        lo = a;
        int a2 = a, b2 = n;
        while (a2 < b2) { int m = (a2 + b2) >> 1; if (batch[m] < g + 1) a2 = m + 1; else b2 = m; }
        hi = a2;
    }
    lo = __shfl(lo, 0); hi = __shfl(hi, 0);
    float a0 = 0.f, a1 = 0.f, a2 = 0.f, a3 = 0.f;
    for (int i = lo; i < hi; i++) {
        ushort4 v = *(const ushort4*)(h + (size_t)i * 256 + lane * 4);
        a0 += bf2f(v.x); a1 += bf2f(v.y); a2 += bf2f(v.z); a3 += bf2f(v.w);
    }
    float inv = 1.0f / fmaxf((float)(hi - lo), 1.0f);
    ushort4 o;
    o.x = f2bf(a0 * inv); o.y = f2bf(a1 * inv); o.z = f2bf(a2 * inv); o.w = f2bf(a3 * inv);
    *(ushort4*)(g0 + (size_t)g * 256 + lane * 4) = o;
}

__launch_bounds__(256)
__global__ void ln_kernel(const float* __restrict__ g2, const float* __restrict__ gamma,
                          const float* __restrict__ beta, float* __restrict__ out, int rows) {
    int row = blockIdx.x * 4 + (threadIdx.x >> 6);
    int lane = threadIdx.x & 63;
    if (row >= rows) return;
    const float* r = g2 + (size_t)row * 768;
    float v[12];
    float s = 0.f, s2 = 0.f;
    #pragma unroll
    for (int j = 0; j < 12; j++) {
        v[j] = r[lane + 64 * j];
        s += v[j];
        s2 += v[j] * v[j];
    }
    #pragma unroll
    for (int off = 32; off > 0; off >>= 1) {
        s += __shfl_down(s, off);
        s2 += __shfl_down(s2, off);
    }
    s = __shfl(s, 0);
    s2 = __shfl(s2, 0);
    float mu = s * (1.0f / 768.0f);
    float var = s2 * (1.0f / 768.0f) - mu * mu;
    float inv = rsqrtf(var + 1e-5f);
    #pragma unroll
    for (int j = 0; j < 12; j++) {
        int c = lane + 64 * j;
        out[(size_t)row * 768 + c] = (v[j] - mu) * inv * gamma[c] + beta[c];
    }
}

// ---------------------------------------------------------------------------

extern "C" void kernel_launch(void* const* d_in, const int* in_sizes, int n_in,
                              void* d_out, int out_size, void* d_ws, size_t ws_size,
                              hipStream_t stream) {
    const float* x    = (const float*)d_in[0];
    const int* eidx   = (const int*)d_in[1];
    const int* batch  = (const int*)d_in[2];
    const float* W1   = (const float*)d_in[3];
    const float* b1   = (const float*)d_in[4];
    const float* W2   = (const float*)d_in[5];
    const float* b2   = (const float*)d_in[6];
    const float* W3   = (const float*)d_in[7];
    const float* b3   = (const float*)d_in[8];
    const float* P1   = (const float*)d_in[9];
    const float* pb1  = (const float*)d_in[10];
    const float* P2   = (const float*)d_in[11];
    const float* pb2  = (const float*)d_in[12];
    const float* ln_g = (const float*)d_in[13];
    const float* ln_b = (const float*)d_in[14];
    float* out = (float*)d_out;

    const int N = in_sizes[2];            // 50000
    const int E = in_sizes[1] / 2;        // 800000
    const int F_IN = in_sizes[0] / N;     // 128
    const int H = in_sizes[4];            // 256
    const int D = in_sizes[12];           // 768
    const int G = out_size / D;           // 1024
    const int NPAD = (N + 127) & ~127;
    const int NB = (N + 511) / 512;       // scan blocks (<=128)

    const int* src = eidx;
    const int* dst = eidx + E;

    char* ws = (char*)d_ws;
    size_t off = 0;
    auto alloc = [&](size_t bytes) -> char* {
        char* p = ws + off;
        off = (off + bytes + 255) & ~(size_t)255;
        return p;
    };
    int*   cnt      = (int*)alloc((size_t)NPAD * 4);   // cnt & fill contiguous -> one memset
    int*   fill     = (int*)alloc((size_t)NPAD * 4);
    float* dinv     = (float*)alloc((size_t)NPAD * 4);
    int*   row_ptr  = (int*)alloc((size_t)(N + 1) * 4);
    int*   bsum     = (int*)alloc(128 * 4);
    int*   csr      = (int*)alloc((size_t)E * 4);
    unsigned short* xh  = (unsigned short*)alloc((size_t)(N + 1) * F_IN * 2);  // x̂, +dummy row
    unsigned short* Wt1 = (unsigned short*)alloc((size_t)F_IN * H * 2);
    unsigned short* Wt2 = (unsigned short*)alloc((size_t)H * H * 2);
    unsigned short* Wt3 = (unsigned short*)alloc((size_t)H * H * 2);
    unsigned short* Pt1 = (unsigned short*)alloc((size_t)H * H * 2);
    unsigned short* Pt2 = (unsigned short*)alloc((size_t)H * D * 2);
    unsigned short* t1  = (unsigned short*)alloc((size_t)N * F_IN * 2);        // Σ x̂
    unsigned short* tA  = (unsigned short*)alloc((size_t)N * H * 2);           // Σ ĥ (shared)
    unsigned short* hh1 = (unsigned short*)alloc((size_t)(N + 1) * H * 2);     // ĥ1, +dummy
    unsigned short* hh2 = (unsigned short*)alloc((size_t)(N + 1) * H * 2);     // ĥ2, +dummy
    unsigned short* h3  = (unsigned short*)alloc((size_t)N * H * 2);
    unsigned short* g0b = (unsigned short*)alloc((size_t)G * H * 2);
    unsigned short* g1b = (unsigned short*)alloc((size_t)G * H * 2);
    float* g2 = (float*)alloc((size_t)G * D * 4);
    (void)ws_size; (void)n_in;

    // --- CSR build -----------------------------------------------------------
    hipMemsetAsync(cnt, 0, (size_t)2 * NPAD * 4, stream);
    count_kernel<<<(E + 255) / 256, 256, 0, stream>>>(dst, E, cnt);
    scanA<<<NB, 512, 0, stream>>>(cnt, N, bsum, dinv);
    scanC<<<NB, 512, 0, stream>>>(cnt, N, bsum, E, row_ptr);
    scatter_kernel<<<(E + 255) / 256, 256, 0, stream>>>(src, dst, E, row_ptr, fill, csr);

    // --- conversions (one launch) -------------------------------------------
    {
        int n4 = N * F_IN / 4;
        int tot = F_IN * H + 3 * H * H + H * D;
        int total = n4 + tot + 640;
        convert_all<<<(total + 255) / 256, 256, 0, stream>>>(
            x, dinv, xh, n4, W1, W2, W3, P1, P2, Wt1, Wt2, Wt3, Pt1, Pt2, F_IN, H, D,
            xh + (size_t)N * F_IN, hh1 + (size_t)N * H, hh2 + (size_t)N * H);
    }

    // --- GCN layers (aggregate-first, ĥ-space) ------------------------------
    int agg_grid = (N + 3) / 4;
    int mtiles = (N + 127) / 128;

    // layer 1: t1 = x̂[i] + Σ x̂[src]; ĥ1 = di*relu(di*(t1 W1) + b1)
    aggregate128<<<agg_grid, 256, 0, stream>>>(xh, row_ptr, csr, t1, N, N);
    wgemm<128, 1, 0, 0, 1><<<dim3(2, mtiles), 256, 0, stream>>>(t1, Wt1, b1, nullptr, dinv, hh1, N, H, 2);

    // layer 2: t2 = ĥ1[i] + Σ ĥ1[src]; ĥ2 = di*(relu(di*(t2 W2)+b2) + ĥ1/di)
    aggregate256<<<agg_grid, 256, 0, stream>>>(hh1, row_ptr, csr, tA, N, N);
    wgemm<256, 1, 1, 0, 1><<<dim3(2, mtiles), 256, 0, stream>>>(tA, Wt2, b2, hh1, dinv, hh2, N, H, 2);

    // layer 3: t3 = ĥ2[i] + Σ ĥ2[src]; h3 = relu(di*(t3 W3)+b3) + ĥ2/di
    aggregate256<<<agg_grid, 256, 0, stream>>>(hh2, row_ptr, csr, tA, N, N);
    wgemm<256, 1, 1, 0, 2><<<dim3(2, mtiles), 256, 0, stream>>>(tA, Wt3, b3, hh2, dinv, h3, N, H, 2);

    // --- pool + MLP + LN -----------------------------------------------------
    pool_kernel<<<(G + 3) / 4, 256, 0, stream>>>(h3, batch, g0b, N, G);
    wgemm<256, 1, 0, 0, 0><<<dim3(4, G / 128), 256, 0, stream>>>(g0b, Pt1, pb1, nullptr, nullptr, g1b, G, H, 1);
    wgemm<256, 0, 0, 1, 0><<<dim3(12, G / 128), 256, 0, stream>>>(g1b, Pt2, pb2, nullptr, nullptr, g2, G, D, 1);
    ln_kernel<<<G / 4, 256, 0, stream>>>(g2, ln_g, ln_b, out, G);
}

// Round 11
// 425.069 us; speedup vs baseline: 1.2020x; 1.0537x over previous
//
#include <hip/hip_runtime.h>

// ---------------------------------------------------------------------------
// GraphEncoder round 11:
//  - scatter WITHOUT atomics: count_kernel records each edge's rank
//    (= atomicAdd return), scatter becomes pure read + random write.
//  - layer wgemms: grid.x=4 / ntiles=1 (1564 blocks, ~6/CU) -- they are
//    latency-bound (R9: 1.1 TB/s), so block count > per-block work.
//  - aggregation untouched: measured MSHR-bound gather ceiling (~7 TB/s
//    demand, 58us per 256-col pass; ~145us total floor for 3 layers).
// ---------------------------------------------------------------------------

typedef __attribute__((ext_vector_type(8))) short short8;
typedef __attribute__((ext_vector_type(4))) float f32x4;

__device__ __forceinline__ float bf2f(unsigned short s) {
    union { unsigned u; float f; } v;
    v.u = ((unsigned)s) << 16;
    return v.f;
}
__device__ __forceinline__ unsigned short f2bf(float f) {
    union { float f; unsigned u; } v;
    v.f = f;
    unsigned r = (v.u + 0x7FFFu + ((v.u >> 16) & 1u)) >> 16;
    return (unsigned short)r;
}

// ---------------------------- CSR build ------------------------------------

// Counts in-degree AND records each edge's arrival rank (unique slot).
__global__ void count_kernel(const int* __restrict__ dst, int E, int* __restrict__ cnt,
                             int* __restrict__ rank) {
    int e = blockIdx.x * blockDim.x + threadIdx.x;
    if (e < E) rank[e] = atomicAdd(&cnt[dst[e]], 1);
}

__global__ void scanA(const int* __restrict__ cnt, int n, int* __restrict__ bsum,
                      float* __restrict__ dinv) {
    int tid = threadIdx.x, lane = tid & 63, w = tid >> 6;
    int i = blockIdx.x * 512 + tid;
    int v = (i < n) ? cnt[i] : 0;
    if (i < n) dinv[i] = rsqrtf((float)v + 1.0f);
    int s = v;
    #pragma unroll
    for (int off = 1; off < 64; off <<= 1) s += __shfl_xor(s, off);
    __shared__ int ws[8];
    if (lane == 0) ws[w] = s;
    __syncthreads();
    if (tid == 0) {
        int t = 0;
        #pragma unroll
        for (int j = 0; j < 8; j++) t += ws[j];
        bsum[blockIdx.x] = t;
    }
}

__global__ void scanC(const int* __restrict__ cnt, int n, const int* __restrict__ bsum,
                      int E, int* __restrict__ row_ptr) {
    int tid = threadIdx.x, lane = tid & 63, w = tid >> 6;
    int i = blockIdx.x * 512 + tid;
    __shared__ int s_boff;
    if (tid < 64) {
        int acc = 0;
        for (int b = tid; b < blockIdx.x; b += 64) acc += bsum[b];
        #pragma unroll
        for (int off = 1; off < 64; off <<= 1) acc += __shfl_xor(acc, off);
        if (tid == 0) s_boff = acc;
    }
    int v = (i < n) ? cnt[i] : 0;
    int incl = v;
    #pragma unroll
    for (int off = 1; off < 64; off <<= 1) {
        int t = __shfl_up(incl, off);
        if (lane >= off) incl += t;
    }
    __shared__ int ws[8];
    if (lane == 63) ws[w] = incl;
    __syncthreads();
    int woff = 0;
    for (int j = 0; j < w; j++) woff += ws[j];
    if (i < n) row_ptr[i] = s_boff + woff + incl - v;
    if (blockIdx.x == 0 && tid == 0) row_ptr[n] = E;
}

// No atomics: slot = row_ptr[dst] + rank (unique per edge by construction).
__global__ void scatter_kernel(const int* __restrict__ src, const int* __restrict__ dst, int E,
                               const int* __restrict__ row_ptr, const int* __restrict__ rank,
                               int* __restrict__ csr) {
    int e = blockIdx.x * blockDim.x + threadIdx.x;
    if (e < E) csr[row_ptr[dst[e]] + rank[e]] = src[e];
}

// ---------------------------- conversions (fused) --------------------------

__global__ void convert_all(const float* __restrict__ x, const float* __restrict__ dinv,
                            unsigned short* __restrict__ xh, int n4,
                            const float* __restrict__ W1, const float* __restrict__ W2,
                            const float* __restrict__ W3, const float* __restrict__ P1,
                            const float* __restrict__ P2,
                            unsigned short* __restrict__ Wt1, unsigned short* __restrict__ Wt2,
                            unsigned short* __restrict__ Wt3, unsigned short* __restrict__ Pt1,
                            unsigned short* __restrict__ Pt2,
                            int F_IN, int H, int D,
                            unsigned short* __restrict__ zx,
                            unsigned short* __restrict__ z1,
                            unsigned short* __restrict__ z2) {
    int idx = blockIdx.x * blockDim.x + threadIdx.x;
    if (idx < n4) {
        float di = dinv[idx >> 5];
        float4 v = ((const float4*)x)[idx];
        ushort4 o;
        o.x = f2bf(di * v.x); o.y = f2bf(di * v.y);
        o.z = f2bf(di * v.z); o.w = f2bf(di * v.w);
        ((ushort4*)xh)[idx] = o;
        return;
    }
    int t = idx - n4;
    int n1 = F_IN * H, n2 = H * H, n5 = H * D;
    const float* W; unsigned short* O; int N;
    if (t < n1)              { W = W1; O = Wt1; N = H; }
    else if ((t -= n1) < n2) { W = W2; O = Wt2; N = H; }
    else if ((t -= n2) < n2) { W = W3; O = Wt3; N = H; }
    else if ((t -= n2) < n2) { W = P1; O = Pt1; N = H; }
    else if ((t -= n2) < n5) { W = P2; O = Pt2; N = D; }
    else {
        t -= n5;
        if (t < 128) zx[t] = 0;
        else if (t < 384) z1[t - 128] = 0;
        else if (t < 640) z2[t - 384] = 0;
        return;
    }
    int k = t / N, n = t - k * N;
    int K = (W == W1) ? F_IN : H;
    O[(size_t)n * K + k] = f2bf(W[t]);
}

// ---------------------------- aggregation (pure sum) -----------------------

__launch_bounds__(256)
__global__ void aggregate256(const unsigned short* __restrict__ h,
                             const int* __restrict__ row_ptr,
                             const int* __restrict__ csr,
                             unsigned short* __restrict__ out, int n, int zrow) {
    int node = blockIdx.x * 4 + (threadIdx.x >> 6);
    int lane = threadIdx.x & 63;
    if (node >= n) return;
    int half = lane >> 5;
    int cl = lane & 31;
    float acc[8] = {0, 0, 0, 0, 0, 0, 0, 0};
    if (half == 0) {
        short8 sv = *(const short8*)(h + (size_t)node * 256 + cl * 8);
        #pragma unroll
        for (int c = 0; c < 8; c++) acc[c] = bf2f((unsigned short)sv[c]);
    }
    int beg = row_ptr[node], end = row_ptr[node + 1];
    for (int base = beg; base < end; base += 64) {
        int k = base + lane;
        int mi = (k < end) ? csr[k] : zrow;
        int cnt = min(64, end - base);
        for (int j = 0; j < cnt; j += 16) {
            int idx[8]; short8 vv[8];
            #pragma unroll
            for (int u = 0; u < 8; u++) idx[u] = __shfl(mi, j + 2 * u + half);
            #pragma unroll
            for (int u = 0; u < 8; u++) vv[u] = *(const short8*)(h + (size_t)idx[u] * 256 + cl * 8);
            #pragma unroll
            for (int u = 0; u < 8; u++)
                #pragma unroll
                for (int c = 0; c < 8; c++) acc[c] += bf2f((unsigned short)vv[u][c]);
        }
    }
    #pragma unroll
    for (int c = 0; c < 8; c++) acc[c] += __shfl_xor(acc[c], 32);
    if (half == 0) {
        short8 o;
        #pragma unroll
        for (int c = 0; c < 8; c++) o[c] = (short)f2bf(acc[c]);
        *(short8*)(out + (size_t)node * 256 + cl * 8) = o;
    }
}

__launch_bounds__(256)
__global__ void aggregate128(const unsigned short* __restrict__ h,
                             const int* __restrict__ row_ptr,
                             const int* __restrict__ csr,
                             unsigned short* __restrict__ out, int n, int zrow) {
    int node = blockIdx.x * 4 + (threadIdx.x >> 6);
    int lane = threadIdx.x & 63;
    if (node >= n) return;
    int qtr = lane >> 4;
    int cl = lane & 15;
    float acc[8] = {0, 0, 0, 0, 0, 0, 0, 0};
    if (qtr == 0) {
        short8 sv = *(const short8*)(h + (size_t)node * 128 + cl * 8);
        #pragma unroll
        for (int c = 0; c < 8; c++) acc[c] = bf2f((unsigned short)sv[c]);
    }
    int beg = row_ptr[node], end = row_ptr[node + 1];
    for (int base = beg; base < end; base += 64) {
        int k = base + lane;
        int mi = (k < end) ? csr[k] : zrow;
        int cnt = min(64, end - base);
        for (int j = 0; j < cnt; j += 32) {
            int idx[8]; short8 vv[8];
            #pragma unroll
            for (int u = 0; u < 8; u++) idx[u] = __shfl(mi, j + 4 * u + qtr);
            #pragma unroll
            for (int u = 0; u < 8; u++) vv[u] = *(const short8*)(h + (size_t)idx[u] * 128 + cl * 8);
            #pragma unroll
            for (int u = 0; u < 8; u++)
                #pragma unroll
                for (int c = 0; c < 8; c++) acc[c] += bf2f((unsigned short)vv[u][c]);
        }
    }
    #pragma unroll
    for (int c = 0; c < 8; c++) {
        acc[c] += __shfl_xor(acc[c], 16);
        acc[c] += __shfl_xor(acc[c], 32);
    }
    if (qtr == 0) {
        short8 o;
        #pragma unroll
        for (int c = 0; c < 8; c++) o[c] = (short)f2bf(acc[c]);
        *(short8*)(out + (size_t)node * 128 + cl * 8) = o;
    }
}

// ---------------------------- wgemm ----------------------------------------
// C = epi(A[M,K] @ Bt[N,K]^T). 256-thr blocks = 4 waves x 32 rows (128 rows).
// A frags in registers; per 64-col tile B staged to LDS; LDS-transpose
// epilogue -> coalesced vectorized residual loads + stores.
// SCALE: 0 plain; 1: v=relu(di*acc+b)[+res/di], store di*v; 2: ...store v.

template<int K, int RELU, int RES, int OUTF32, int SCALE>
__launch_bounds__(256)
__global__ void wgemm(const unsigned short* __restrict__ A,
                      const unsigned short* __restrict__ Bt,
                      const float* __restrict__ bias,
                      const unsigned short* __restrict__ residual,
                      const float* __restrict__ dinv,
                      void* __restrict__ Cout,
                      int M, int N, int ntiles) {
    constexpr int KK = K / 32;
    constexpr int S = K + 8;           // B-stage stride (shorts)
    constexpr int CS = 65;             // fp32 transpose stride (floats)
    constexpr int BSZ = 64 * S * 2;
    constexpr int CSZ = 128 * CS * 4;
    constexpr int SM = BSZ > CSZ ? BSZ : CSZ;
    __shared__ __align__(16) char smraw[SM];
    unsigned short* Bs = (unsigned short*)smraw;
    float* Cs = (float*)smraw;
    constexpr int CPR = K / 8;

    int tid = threadIdx.x;
    int wave = tid >> 6, lane = tid & 63;
    int r = lane & 15, q = lane >> 4;
    int mr = blockIdx.y * 128 + wave * 32;
    int nbase = blockIdx.x * ntiles * 64;

    short8 a[2][KK];
    #pragma unroll
    for (int mi = 0; mi < 2; mi++) {
        int arow = mr + mi * 16 + r;
        bool ok = arow < M;
        const unsigned short* ap = A + (size_t)(ok ? arow : 0) * K;
        #pragma unroll
        for (int kk = 0; kk < KK; kk++) {
            short8 v = *(const short8*)(ap + kk * 32 + q * 8);
            if (!ok) v = (short8){0, 0, 0, 0, 0, 0, 0, 0};
            a[mi][kk] = v;
        }
    }

    for (int t = 0; t < ntiles; t++) {
        int n0 = nbase + t * 64;
        if (t > 0) __syncthreads();   // previous tile's LDS reads complete
        #pragma unroll
        for (int pass = 0; pass < 64 * CPR / 256; pass++) {
            int f = pass * 256 + tid;
            int row = f / CPR, ch = f % CPR;
            *(short8*)&Bs[row * S + ch * 8] =
                *(const short8*)(Bt + (size_t)(n0 + row) * K + ch * 8);
        }
        __syncthreads();

        f32x4 acc[2][4];
        #pragma unroll
        for (int mi = 0; mi < 2; mi++)
            #pragma unroll
            for (int j = 0; j < 4; j++) acc[mi][j] = (f32x4){0.f, 0.f, 0.f, 0.f};

        #pragma unroll
        for (int kk = 0; kk < KK; kk++) {
            short8 b[4];
            #pragma unroll
            for (int j = 0; j < 4; j++)
                b[j] = *(short8*)&Bs[(j * 16 + r) * S + kk * 32 + q * 8];
            #pragma unroll
            for (int mi = 0; mi < 2; mi++)
                #pragma unroll
                for (int j = 0; j < 4; j++)
                    acc[mi][j] = __builtin_amdgcn_mfma_f32_16x16x32_bf16(a[mi][kk], b[j], acc[mi][j], 0, 0, 0);
        }

        // ---- LDS transpose epilogue ----
        __syncthreads();   // B reads done; Cs aliases Bs
        #pragma unroll
        for (int mi = 0; mi < 2; mi++)
            #pragma unroll
            for (int j = 0; j < 4; j++)
                #pragma unroll
                for (int p = 0; p < 4; p++)
                    Cs[(wave * 32 + mi * 16 + q * 4 + p) * CS + j * 16 + r] = acc[mi][j][p];
        __syncthreads();

        int row = tid >> 1;            // 0..127
        int halfc = (tid & 1) * 32;    // 0 or 32
        int grow = blockIdx.y * 128 + row;
        if (grow < M) {
            float vals[32];
            #pragma unroll
            for (int c = 0; c < 8; c++)
                *(f32x4*)&vals[c * 4] = *(f32x4*)&Cs[row * CS + halfc + c * 4];
            float di = 1.f, rdi = 1.f;
            if (SCALE) { di = dinv[grow]; if (RES) rdi = 1.f / di; }
            float bb[32];
            #pragma unroll
            for (int c = 0; c < 8; c++)
                *(f32x4*)&bb[c * 4] = *(const f32x4*)&bias[n0 + halfc + c * 4];
            short8 rv[4];
            if (RES) {
                #pragma unroll
                for (int c = 0; c < 4; c++)
                    rv[c] = *(const short8*)(residual + (size_t)grow * N + n0 + halfc + c * 8);
            }
            #pragma unroll
            for (int c = 0; c < 32; c++) {
                float v = (SCALE ? di * vals[c] : vals[c]) + bb[c];
                if (RELU) v = fmaxf(v, 0.f);
                if (RES) v += bf2f((unsigned short)rv[c / 8][c % 8]) * rdi;
                if (SCALE == 1) v *= di;
                vals[c] = v;
            }
            if (OUTF32) {
                float* cp = (float*)Cout + (size_t)grow * N + n0 + halfc;
                #pragma unroll
                for (int c = 0; c < 8; c++) *(f32x4*)&cp[c * 4] = *(f32x4*)&vals[c * 4];
            } else {
                unsigned short* cp = (unsigned short*)Cout + (size_t)grow * N + n0 + halfc;
                #pragma unroll
                for (int c = 0; c < 4; c++) {
                    short8 o;
                    #pragma unroll
                    for (int u = 0; u < 8; u++) o[u] = (short)f2bf(vals[c * 8 + u]);
                    *(short8*)&cp[c * 8] = o;
                }
            }
        }
    }
}

// ---------------------------- pool / LN ------------------------------------

__launch_bounds__(256)
__global__ void pool_kernel(const unsigned short* __restrict__ h, const int* __restrict__ batch,
                            unsigned short* __restrict__ g0, int n, int G) {
    int g = blockIdx.x * 4 + (threadIdx.x >> 6);
    int lane = threadIdx.x & 63;
    if (g >= G) return;
    int lo = 0, hi = 0;
    if (lane == 0) {
        int a = 0, b = n;
        while (a < b) { int m = (a + b) >> 1; if (batch[m] < g) a = m + 1; else b = m; }
        lo = a;
        int a2 = a, b2 = n;
        while (a2 < b2) { int m = (a2 + b2) >> 1; if (batch[m] < g + 1) a2 = m + 1; else b2 = m; }
        hi = a2;
    }
    lo = __shfl(lo, 0); hi = __shfl(hi, 0);
    float a0 = 0.f, a1 = 0.f, a2 = 0.f, a3 = 0.f;
    for (int i = lo; i < hi; i++) {
        ushort4 v = *(const ushort4*)(h + (size_t)i * 256 + lane * 4);
        a0 += bf2f(v.x); a1 += bf2f(v.y); a2 += bf2f(v.z); a3 += bf2f(v.w);
    }
    float inv = 1.0f / fmaxf((float)(hi - lo), 1.0f);
    ushort4 o;
    o.x = f2bf(a0 * inv); o.y = f2bf(a1 * inv); o.z = f2bf(a2 * inv); o.w = f2bf(a3 * inv);
    *(ushort4*)(g0 + (size_t)g * 256 + lane * 4) = o;
}

__launch_bounds__(256)
__global__ void ln_kernel(const float* __restrict__ g2, const float* __restrict__ gamma,
                          const float* __restrict__ beta, float* __restrict__ out, int rows) {
    int row = blockIdx.x * 4 + (threadIdx.x >> 6);
    int lane = threadIdx.x & 63;
    if (row >= rows) return;
    const float* r = g2 + (size_t)row * 768;
    float v[12];
    float s = 0.f, s2 = 0.f;
    #pragma unroll
    for (int j = 0; j < 12; j++) {
        v[j] = r[lane + 64 * j];
        s += v[j];
        s2 += v[j] * v[j];
    }
    #pragma unroll
    for (int off = 32; off > 0; off >>= 1) {
        s += __shfl_down(s, off);
        s2 += __shfl_down(s2, off);
    }
    s = __shfl(s, 0);
    s2 = __shfl(s2, 0);
    float mu = s * (1.0f / 768.0f);
    float var = s2 * (1.0f / 768.0f) - mu * mu;
    float inv = rsqrtf(var + 1e-5f);
    #pragma unroll
    for (int j = 0; j < 12; j++) {
        int c = lane + 64 * j;
        out[(size_t)row * 768 + c] = (v[j] - mu) * inv * gamma[c] + beta[c];
    }
}

// ---------------------------------------------------------------------------

extern "C" void kernel_launch(void* const* d_in, const int* in_sizes, int n_in,
                              void* d_out, int out_size, void* d_ws, size_t ws_size,
                              hipStream_t stream) {
    const float* x    = (const float*)d_in[0];
    const int* eidx   = (const int*)d_in[1];
    const int* batch  = (const int*)d_in[2];
    const float* W1   = (const float*)d_in[3];
    const float* b1   = (const float*)d_in[4];
    const float* W2   = (const float*)d_in[5];
    const float* b2   = (const float*)d_in[6];
    const float* W3   = (const float*)d_in[7];
    const float* b3   = (const float*)d_in[8];
    const float* P1   = (const float*)d_in[9];
    const float* pb1  = (const float*)d_in[10];
    const float* P2   = (const float*)d_in[11];
    const float* pb2  = (const float*)d_in[12];
    const float* ln_g = (const float*)d_in[13];
    const float* ln_b = (const float*)d_in[14];
    float* out = (float*)d_out;

    const int N = in_sizes[2];            // 50000
    const int E = in_sizes[1] / 2;        // 800000
    const int F_IN = in_sizes[0] / N;     // 128
    const int H = in_sizes[4];            // 256
    const int D = in_sizes[12];           // 768
    const int G = out_size / D;           // 1024
    const int NPAD = (N + 127) & ~127;
    const int NB = (N + 511) / 512;       // scan blocks (<=128)

    const int* src = eidx;
    const int* dst = eidx + E;

    char* ws = (char*)d_ws;
    size_t off = 0;
    auto alloc = [&](size_t bytes) -> char* {
        char* p = ws + off;
        off = (off + bytes + 255) & ~(size_t)255;
        return p;
    };
    int*   cnt      = (int*)alloc((size_t)NPAD * 4);
    float* dinv     = (float*)alloc((size_t)NPAD * 4);
    int*   row_ptr  = (int*)alloc((size_t)(N + 1) * 4);
    int*   bsum     = (int*)alloc(128 * 4);
    int*   rank     = (int*)alloc((size_t)E * 4);
    int*   csr      = (int*)alloc((size_t)E * 4);
    unsigned short* xh  = (unsigned short*)alloc((size_t)(N + 1) * F_IN * 2);  // x̂, +dummy row
    unsigned short* Wt1 = (unsigned short*)alloc((size_t)F_IN * H * 2);
    unsigned short* Wt2 = (unsigned short*)alloc((size_t)H * H * 2);
    unsigned short* Wt3 = (unsigned short*)alloc((size_t)H * H * 2);
    unsigned short* Pt1 = (unsigned short*)alloc((size_t)H * H * 2);
    unsigned short* Pt2 = (unsigned short*)alloc((size_t)H * D * 2);
    unsigned short* t1  = (unsigned short*)alloc((size_t)N * F_IN * 2);        // Σ x̂
    unsigned short* tA  = (unsigned short*)alloc((size_t)N * H * 2);           // Σ ĥ (shared)
    unsigned short* hh1 = (unsigned short*)alloc((size_t)(N + 1) * H * 2);     // ĥ1, +dummy
    unsigned short* hh2 = (unsigned short*)alloc((size_t)(N + 1) * H * 2);     // ĥ2, +dummy
    unsigned short* h3  = (unsigned short*)alloc((size_t)N * H * 2);
    unsigned short* g0b = (unsigned short*)alloc((size_t)G * H * 2);
    unsigned short* g1b = (unsigned short*)alloc((size_t)G * H * 2);
    float* g2 = (float*)alloc((size_t)G * D * 4);
    (void)ws_size; (void)n_in;

    // --- CSR build -----------------------------------------------------------
    hipMemsetAsync(cnt, 0, (size_t)NPAD * 4, stream);
    count_kernel<<<(E + 255) / 256, 256, 0, stream>>>(dst, E, cnt, rank);
    scanA<<<NB, 512, 0, stream>>>(cnt, N, bsum, dinv);
    scanC<<<NB, 512, 0, stream>>>(cnt, N, bsum, E, row_ptr);
    scatter_kernel<<<(E + 255) / 256, 256, 0, stream>>>(src, dst, E, row_ptr, rank, csr);

    // --- conversions (one launch) -------------------------------------------
    {
        int n4 = N * F_IN / 4;
        int tot = F_IN * H + 3 * H * H + H * D;
        int total = n4 + tot + 640;
        convert_all<<<(total + 255) / 256, 256, 0, stream>>>(
            x, dinv, xh, n4, W1, W2, W3, P1, P2, Wt1, Wt2, Wt3, Pt1, Pt2, F_IN, H, D,
            xh + (size_t)N * F_IN, hh1 + (size_t)N * H, hh2 + (size_t)N * H);
    }

    // --- GCN layers (aggregate-first, ĥ-space) ------------------------------
    int agg_grid = (N + 3) / 4;
    int mtiles = (N + 127) / 128;

    // layer 1: t1 = x̂[i] + Σ x̂[src]; ĥ1 = di*relu(di*(t1 W1) + b1)
    aggregate128<<<agg_grid, 256, 0, stream>>>(xh, row_ptr, csr, t1, N, N);
    wgemm<128, 1, 0, 0, 1><<<dim3(4, mtiles), 256, 0, stream>>>(t1, Wt1, b1, nullptr, dinv, hh1, N, H, 1);

    // layer 2: t2 = ĥ1[i] + Σ ĥ1[src]; ĥ2 = di*(relu(di*(t2 W2)+b2) + ĥ1/di)
    aggregate256<<<agg_grid, 256, 0, stream>>>(hh1, row_ptr, csr, tA, N, N);
    wgemm<256, 1, 1, 0, 1><<<dim3(4, mtiles), 256, 0, stream>>>(tA, Wt2, b2, hh1, dinv, hh2, N, H, 1);

    // layer 3: t3 = ĥ2[i] + Σ ĥ2[src]; h3 = relu(di*(t3 W3)+b3) + ĥ2/di
    aggregate256<<<agg_grid, 256, 0, stream>>>(hh2, row_ptr, csr, tA, N, N);
    wgemm<256, 1, 1, 0, 2><<<dim3(4, mtiles), 256, 0, stream>>>(tA, Wt3, b3, hh2, dinv, h3, N, H, 1);

    // --- pool + MLP + LN -----------------------------------------------------
    pool_kernel<<<(G + 3) / 4, 256, 0, stream>>>(h3, batch, g0b, N, G);
    wgemm<256, 1, 0, 0, 0><<<dim3(4, G / 128), 256, 0, stream>>>(g0b, Pt1, pb1, nullptr, nullptr, g1b, G, H, 1);
    wgemm<256, 0, 0, 1, 0><<<dim3(12, G / 128), 256, 0, stream>>>(g1b, Pt2, pb2, nullptr, nullptr, g2, G, D, 1);
    ln_kernel<<<G / 4, 256, 0, stream>>>(g2, ln_g, ln_b, out, G);
}

// Round 12
// 371.903 us; speedup vs baseline: 1.3738x; 1.1430x over previous
//
#include <hip/hip_runtime.h>

// ---------------------------------------------------------------------------
// GraphEncoder round 12: fp8-e4m3 gather shadows.
//   Aggregation is line-concurrency-bound (8 lines/edge @ 512B bf16 rows,
//   ~7 TB/s demand ceiling, 3 designs all at ~58.5us). Halve lines: gathers
//   read a fp8 shadow copy (256B/row); bf16 master kept for GEMM-A/residual.
//   HW cvt (v_cvt_pk_f32_fp8) decodes 2 elems/op. Predicted absmax 0.03-0.06
//   (threshold 0.0734); REVERT if it fails.
// ---------------------------------------------------------------------------

typedef __attribute__((ext_vector_type(8))) short short8;
typedef __attribute__((ext_vector_type(4))) float f32x4;
typedef __attribute__((ext_vector_type(2))) float f32x2;

__device__ __forceinline__ float bf2f(unsigned short s) {
    union { unsigned u; float f; } v;
    v.u = ((unsigned)s) << 16;
    return v.f;
}
__device__ __forceinline__ unsigned short f2bf(float f) {
    union { float f; unsigned u; } v;
    v.f = f;
    unsigned r = (v.u + 0x7FFFu + ((v.u >> 16) & 1u)) >> 16;
    return (unsigned short)r;
}

// accumulate 8 fp8 values (two packed dwords) into acc[0..8)
__device__ __forceinline__ void acc8_fp8(unsigned int lo, unsigned int hi, float* acc) {
    f32x2 p0 = __builtin_amdgcn_cvt_pk_f32_fp8(lo, false);
    f32x2 p1 = __builtin_amdgcn_cvt_pk_f32_fp8(lo, true);
    f32x2 p2 = __builtin_amdgcn_cvt_pk_f32_fp8(hi, false);
    f32x2 p3 = __builtin_amdgcn_cvt_pk_f32_fp8(hi, true);
    acc[0] += p0[0]; acc[1] += p0[1]; acc[2] += p1[0]; acc[3] += p1[1];
    acc[4] += p2[0]; acc[5] += p2[1]; acc[6] += p3[0]; acc[7] += p3[1];
}

// ---------------------------- CSR build ------------------------------------

__global__ void count_kernel(const int* __restrict__ dst, int E, int* __restrict__ cnt,
                             int* __restrict__ rank) {
    int e = blockIdx.x * blockDim.x + threadIdx.x;
    if (e < E) rank[e] = atomicAdd(&cnt[dst[e]], 1);
}

__global__ void scanA(const int* __restrict__ cnt, int n, int* __restrict__ bsum,
                      float* __restrict__ dinv) {
    int tid = threadIdx.x, lane = tid & 63, w = tid >> 6;
    int i = blockIdx.x * 512 + tid;
    int v = (i < n) ? cnt[i] : 0;
    if (i < n) dinv[i] = rsqrtf((float)v + 1.0f);
    int s = v;
    #pragma unroll
    for (int off = 1; off < 64; off <<= 1) s += __shfl_xor(s, off);
    __shared__ int ws[8];
    if (lane == 0) ws[w] = s;
    __syncthreads();
    if (tid == 0) {
        int t = 0;
        #pragma unroll
        for (int j = 0; j < 8; j++) t += ws[j];
        bsum[blockIdx.x] = t;
    }
}

__global__ void scanC(const int* __restrict__ cnt, int n, const int* __restrict__ bsum,
                      int E, int* __restrict__ row_ptr) {
    int tid = threadIdx.x, lane = tid & 63, w = tid >> 6;
    int i = blockIdx.x * 512 + tid;
    __shared__ int s_boff;
    if (tid < 64) {
        int acc = 0;
        for (int b = tid; b < blockIdx.x; b += 64) acc += bsum[b];
        #pragma unroll
        for (int off = 1; off < 64; off <<= 1) acc += __shfl_xor(acc, off);
        if (tid == 0) s_boff = acc;
    }
    int v = (i < n) ? cnt[i] : 0;
    int incl = v;
    #pragma unroll
    for (int off = 1; off < 64; off <<= 1) {
        int t = __shfl_up(incl, off);
        if (lane >= off) incl += t;
    }
    __shared__ int ws[8];
    if (lane == 63) ws[w] = incl;
    __syncthreads();
    int woff = 0;
    for (int j = 0; j < w; j++) woff += ws[j];
    if (i < n) row_ptr[i] = s_boff + woff + incl - v;
    if (blockIdx.x == 0 && tid == 0) row_ptr[n] = E;
}

__global__ void scatter_kernel(const int* __restrict__ src, const int* __restrict__ dst, int E,
                               const int* __restrict__ row_ptr, const int* __restrict__ rank,
                               int* __restrict__ csr) {
    int e = blockIdx.x * blockDim.x + threadIdx.x;
    if (e < E) csr[row_ptr[dst[e]] + rank[e]] = src[e];
}

// ---------------------------- conversions (fused) --------------------------
// [0, n4):       x̂ = dinv*x -> fp8 (gather shadow; no bf16 copy needed)
// [n4, n4+tot):  weight transpose W[K,N] fp32 -> Wt[N,K] bf16
// tail:          zero fp8 dummy rows (xf8:128B, h1f8:256B, h2f8:256B)

__global__ void convert_all(const float* __restrict__ x, const float* __restrict__ dinv,
                            unsigned char* __restrict__ xf8, int n4,
                            const float* __restrict__ W1, const float* __restrict__ W2,
                            const float* __restrict__ W3, const float* __restrict__ P1,
                            const float* __restrict__ P2,
                            unsigned short* __restrict__ Wt1, unsigned short* __restrict__ Wt2,
                            unsigned short* __restrict__ Wt3, unsigned short* __restrict__ Pt1,
                            unsigned short* __restrict__ Pt2,
                            int F_IN, int H, int D,
                            unsigned char* __restrict__ zx,
                            unsigned char* __restrict__ z1,
                            unsigned char* __restrict__ z2) {
    int idx = blockIdx.x * blockDim.x + threadIdx.x;
    if (idx < n4) {
        float di = dinv[idx >> 5];
        float4 v = ((const float4*)x)[idx];
        unsigned int p = 0;
        p = __builtin_amdgcn_cvt_pk_fp8_f32(di * v.x, di * v.y, p, false);
        p = __builtin_amdgcn_cvt_pk_fp8_f32(di * v.z, di * v.w, p, true);
        ((unsigned int*)xf8)[idx] = p;
        return;
    }
    int t = idx - n4;
    int n1 = F_IN * H, n2 = H * H, n5 = H * D;
    const float* W; unsigned short* O; int N;
    if (t < n1)              { W = W1; O = Wt1; N = H; }
    else if ((t -= n1) < n2) { W = W2; O = Wt2; N = H; }
    else if ((t -= n2) < n2) { W = W3; O = Wt3; N = H; }
    else if ((t -= n2) < n2) { W = P1; O = Pt1; N = H; }
    else if ((t -= n2) < n5) { W = P2; O = Pt2; N = D; }
    else {
        t -= n5;
        if (t < 128) zx[t] = 0;
        else if (t < 384) z1[t - 128] = 0;
        else if (t < 640) z2[t - 384] = 0;
        return;
    }
    int k = t / N, n = t - k * N;
    int K = (W == W1) ? F_IN : H;
    O[(size_t)n * K + k] = f2bf(W[t]);
}

// ---------------------------- aggregation (fp8 gathers) --------------------
// t[node] = self + sum_e h[src_e], reading 256B fp8 rows (4 lines/edge).
// bf16 output. Dummy row `zrow` (zeroed) pads tails.

__launch_bounds__(256)
__global__ void aggregate256(const unsigned char* __restrict__ hf8,
                             const int* __restrict__ row_ptr,
                             const int* __restrict__ csr,
                             unsigned short* __restrict__ out, int n, int zrow) {
    int node = blockIdx.x * 4 + (threadIdx.x >> 6);
    int lane = threadIdx.x & 63;
    if (node >= n) return;
    int half = lane >> 5;          // which edge of the pair
    int cl = lane & 31;            // 8-col chunk
    float acc[8] = {0, 0, 0, 0, 0, 0, 0, 0};
    if (half == 0) {
        uint2 sv = *(const uint2*)(hf8 + (size_t)node * 256 + cl * 8);
        acc8_fp8(sv.x, sv.y, acc);
    }
    int beg = row_ptr[node], end = row_ptr[node + 1];
    for (int base = beg; base < end; base += 64) {
        int k = base + lane;
        int mi = (k < end) ? csr[k] : zrow;
        int cnt = min(64, end - base);
        for (int j = 0; j < cnt; j += 16) {
            int idx[8]; uint2 vv[8];
            #pragma unroll
            for (int u = 0; u < 8; u++) idx[u] = __shfl(mi, j + 2 * u + half);
            #pragma unroll
            for (int u = 0; u < 8; u++) vv[u] = *(const uint2*)(hf8 + (size_t)idx[u] * 256 + cl * 8);
            #pragma unroll
            for (int u = 0; u < 8; u++) acc8_fp8(vv[u].x, vv[u].y, acc);
        }
    }
    #pragma unroll
    for (int c = 0; c < 8; c++) acc[c] += __shfl_xor(acc[c], 32);
    if (half == 0) {
        short8 o;
        #pragma unroll
        for (int c = 0; c < 8; c++) o[c] = (short)f2bf(acc[c]);
        *(short8*)(out + (size_t)node * 256 + cl * 8) = o;
    }
}

// 128-col rows: 128B fp8 (2 lines/edge), 4 edges per wave-instr.
__launch_bounds__(256)
__global__ void aggregate128(const unsigned char* __restrict__ hf8,
                             const int* __restrict__ row_ptr,
                             const int* __restrict__ csr,
                             unsigned short* __restrict__ out, int n, int zrow) {
    int node = blockIdx.x * 4 + (threadIdx.x >> 6);
    int lane = threadIdx.x & 63;
    if (node >= n) return;
    int qtr = lane >> 4;           // which edge of the quad
    int cl = lane & 15;            // 8-col chunk
    float acc[8] = {0, 0, 0, 0, 0, 0, 0, 0};
    if (qtr == 0) {
        uint2 sv = *(const uint2*)(hf8 + (size_t)node * 128 + cl * 8);
        acc8_fp8(sv.x, sv.y, acc);
    }
    int beg = row_ptr[node], end = row_ptr[node + 1];
    for (int base = beg; base < end; base += 64) {
        int k = base + lane;
        int mi = (k < end) ? csr[k] : zrow;
        int cnt = min(64, end - base);
        for (int j = 0; j < cnt; j += 32) {
            int idx[8]; uint2 vv[8];
            #pragma unroll
            for (int u = 0; u < 8; u++) idx[u] = __shfl(mi, j + 4 * u + qtr);
            #pragma unroll
            for (int u = 0; u < 8; u++) vv[u] = *(const uint2*)(hf8 + (size_t)idx[u] * 128 + cl * 8);
            #pragma unroll
            for (int u = 0; u < 8; u++) acc8_fp8(vv[u].x, vv[u].y, acc);
        }
    }
    #pragma unroll
    for (int c = 0; c < 8; c++) {
        acc[c] += __shfl_xor(acc[c], 16);
        acc[c] += __shfl_xor(acc[c], 32);
    }
    if (qtr == 0) {
        short8 o;
        #pragma unroll
        for (int c = 0; c < 8; c++) o[c] = (short)f2bf(acc[c]);
        *(short8*)(out + (size_t)node * 128 + cl * 8) = o;
    }
}

// ---------------------------- wgemm ----------------------------------------
// C = epi(A[M,K] @ Bt[N,K]^T). 256-thr blocks = 4 waves x 32 rows (128 rows).
// A frags in registers; per 64-col tile B staged to LDS; LDS-transpose
// epilogue -> coalesced vectorized residual loads + stores.
// SCALE: 0 plain; 1: v=relu(di*acc+b)[+res/di], store di*v; 2: ...store v.
// FP8O: also store v as fp8 shadow (gather copy for the next aggregate).

template<int K, int RELU, int RES, int OUTF32, int SCALE, int FP8O>
__launch_bounds__(256)
__global__ void wgemm(const unsigned short* __restrict__ A,
                      const unsigned short* __restrict__ Bt,
                      const float* __restrict__ bias,
                      const unsigned short* __restrict__ residual,
                      const float* __restrict__ dinv,
                      void* __restrict__ Cout,
                      unsigned char* __restrict__ f8out,
                      int M, int N, int ntiles) {
    constexpr int KK = K / 32;
    constexpr int S = K + 8;           // B-stage stride (shorts)
    constexpr int CS = 65;             // fp32 transpose stride (floats)
    constexpr int BSZ = 64 * S * 2;
    constexpr int CSZ = 128 * CS * 4;
    constexpr int SM = BSZ > CSZ ? BSZ : CSZ;
    __shared__ __align__(16) char smraw[SM];
    unsigned short* Bs = (unsigned short*)smraw;
    float* Cs = (float*)smraw;
    constexpr int CPR = K / 8;

    int tid = threadIdx.x;
    int wave = tid >> 6, lane = tid & 63;
    int r = lane & 15, q = lane >> 4;
    int mr = blockIdx.y * 128 + wave * 32;
    int nbase = blockIdx.x * ntiles * 64;

    short8 a[2][KK];
    #pragma unroll
    for (int mi = 0; mi < 2; mi++) {
        int arow = mr + mi * 16 + r;
        bool ok = arow < M;
        const unsigned short* ap = A + (size_t)(ok ? arow : 0) * K;
        #pragma unroll
        for (int kk = 0; kk < KK; kk++) {
            short8 v = *(const short8*)(ap + kk * 32 + q * 8);
            if (!ok) v = (short8){0, 0, 0, 0, 0, 0, 0, 0};
            a[mi][kk] = v;
        }
    }

    for (int t = 0; t < ntiles; t++) {
        int n0 = nbase + t * 64;
        if (t > 0) __syncthreads();
        #pragma unroll
        for (int pass = 0; pass < 64 * CPR / 256; pass++) {
            int f = pass * 256 + tid;
            int row = f / CPR, ch = f % CPR;
            *(short8*)&Bs[row * S + ch * 8] =
                *(const short8*)(Bt + (size_t)(n0 + row) * K + ch * 8);
        }
        __syncthreads();

        f32x4 acc[2][4];
        #pragma unroll
        for (int mi = 0; mi < 2; mi++)
            #pragma unroll
            for (int j = 0; j < 4; j++) acc[mi][j] = (f32x4){0.f, 0.f, 0.f, 0.f};

        #pragma unroll
        for (int kk = 0; kk < KK; kk++) {
            short8 b[4];
            #pragma unroll
            for (int j = 0; j < 4; j++)
                b[j] = *(short8*)&Bs[(j * 16 + r) * S + kk * 32 + q * 8];
            #pragma unroll
            for (int mi = 0; mi < 2; mi++)
                #pragma unroll
                for (int j = 0; j < 4; j++)
                    acc[mi][j] = __builtin_amdgcn_mfma_f32_16x16x32_bf16(a[mi][kk], b[j], acc[mi][j], 0, 0, 0);
        }

        // ---- LDS transpose epilogue ----
        __syncthreads();   // B reads done; Cs aliases Bs
        #pragma unroll
        for (int mi = 0; mi < 2; mi++)
            #pragma unroll
            for (int j = 0; j < 4; j++)
                #pragma unroll
                for (int p = 0; p < 4; p++)
                    Cs[(wave * 32 + mi * 16 + q * 4 + p) * CS + j * 16 + r] = acc[mi][j][p];
        __syncthreads();

        int row = tid >> 1;            // 0..127
        int halfc = (tid & 1) * 32;    // 0 or 32
        int grow = blockIdx.y * 128 + row;
        if (grow < M) {
            float vals[32];
            #pragma unroll
            for (int c = 0; c < 8; c++)
                *(f32x4*)&vals[c * 4] = *(f32x4*)&Cs[row * CS + halfc + c * 4];
            float di = 1.f, rdi = 1.f;
            if (SCALE) { di = dinv[grow]; if (RES) rdi = 1.f / di; }
            float bb[32];
            #pragma unroll
            for (int c = 0; c < 8; c++)
                *(f32x4*)&bb[c * 4] = *(const f32x4*)&bias[n0 + halfc + c * 4];
            short8 rv[4];
            if (RES) {
                #pragma unroll
                for (int c = 0; c < 4; c++)
                    rv[c] = *(const short8*)(residual + (size_t)grow * N + n0 + halfc + c * 8);
            }
            #pragma unroll
            for (int c = 0; c < 32; c++) {
                float v = (SCALE ? di * vals[c] : vals[c]) + bb[c];
                if (RELU) v = fmaxf(v, 0.f);
                if (RES) v += bf2f((unsigned short)rv[c / 8][c % 8]) * rdi;
                if (SCALE == 1) v *= di;
                vals[c] = v;
            }
            if (OUTF32) {
                float* cp = (float*)Cout + (size_t)grow * N + n0 + halfc;
                #pragma unroll
                for (int c = 0; c < 8; c++) *(f32x4*)&cp[c * 4] = *(f32x4*)&vals[c * 4];
            } else {
                unsigned short* cp = (unsigned short*)Cout + (size_t)grow * N + n0 + halfc;
                #pragma unroll
                for (int c = 0; c < 4; c++) {
                    short8 o;
                    #pragma unroll
                    for (int u = 0; u < 8; u++) o[u] = (short)f2bf(vals[c * 8 + u]);
                    *(short8*)&cp[c * 8] = o;
                }
            }
            if (FP8O) {
                unsigned int w[8];
                #pragma unroll
                for (int c = 0; c < 8; c++) {
                    unsigned int p = 0;
                    p = __builtin_amdgcn_cvt_pk_fp8_f32(vals[c * 4 + 0], vals[c * 4 + 1], p, false);
                    p = __builtin_amdgcn_cvt_pk_fp8_f32(vals[c * 4 + 2], vals[c * 4 + 3], p, true);
                    w[c] = p;
                }
                unsigned char* fp = f8out + (size_t)grow * N + n0 + halfc;
                *(uint4*)(fp) = make_uint4(w[0], w[1], w[2], w[3]);
                *(uint4*)(fp + 16) = make_uint4(w[4], w[5], w[6], w[7]);
            }
        }
    }
}

// ---------------------------- pool / LN ------------------------------------

__launch_bounds__(256)
__global__ void pool_kernel(const unsigned short* __restrict__ h, const int* __restrict__ batch,
                            unsigned short* __restrict__ g0, int n, int G) {
    int g = blockIdx.x * 4 + (threadIdx.x >> 6);
    int lane = threadIdx.x & 63;
    if (g >= G) return;
    int lo = 0, hi = 0;
    if (lane == 0) {
        int a = 0, b = n;
        while (a < b) { int m = (a + b) >> 1; if (batch[m] < g) a = m + 1; else b = m; }
        lo = a;
        int a2 = a, b2 = n;
        while (a2 < b2) { int m = (a2 + b2) >> 1; if (batch[m] < g + 1) a2 = m + 1; else b2 = m; }
        hi = a2;
    }
    lo = __shfl(lo, 0); hi = __shfl(hi, 0);
    float a0 = 0.f, a1 = 0.f, a2 = 0.f, a3 = 0.f;
    for (int i = lo; i < hi; i++) {
        ushort4 v = *(const ushort4*)(h + (size_t)i * 256 + lane * 4);
        a0 += bf2f(v.x); a1 += bf2f(v.y); a2 += bf2f(v.z); a3 += bf2f(v.w);
    }
    float inv = 1.0f / fmaxf((float)(hi - lo), 1.0f);
    ushort4 o;
    o.x = f2bf(a0 * inv); o.y = f2bf(a1 * inv); o.z = f2bf(a2 * inv); o.w = f2bf(a3 * inv);
    *(ushort4*)(g0 + (size_t)g * 256 + lane * 4) = o;
}

__launch_bounds__(256)
__global__ void ln_kernel(const float* __restrict__ g2, const float* __restrict__ gamma,
                          const float* __restrict__ beta, float* __restrict__ out, int rows) {
    int row = blockIdx.x * 4 + (threadIdx.x >> 6);
    int lane = threadIdx.x & 63;
    if (row >= rows) return;
    const float* r = g2 + (size_t)row * 768;
    float v[12];
    float s = 0.f, s2 = 0.f;
    #pragma unroll
    for (int j = 0; j < 12; j++) {
        v[j] = r[lane + 64 * j];
        s += v[j];
        s2 += v[j] * v[j];
    }
    #pragma unroll
    for (int off = 32; off > 0; off >>= 1) {
        s += __shfl_down(s, off);
        s2 += __shfl_down(s2, off);
    }
    s = __shfl(s, 0);
    s2 = __shfl(s2, 0);
    float mu = s * (1.0f / 768.0f);
    float var = s2 * (1.0f / 768.0f) - mu * mu;
    float inv = rsqrtf(var + 1e-5f);
    #pragma unroll
    for (int j = 0; j < 12; j++) {
        int c = lane + 64 * j;
        out[(size_t)row * 768 + c] = (v[j] - mu) * inv * gamma[c] + beta[c];
    }
}

// ---------------------------------------------------------------------------

extern "C" void kernel_launch(void* const* d_in, const int* in_sizes, int n_in,
                              void* d_out, int out_size, void* d_ws, size_t ws_size,
                              hipStream_t stream) {
    const float* x    = (const float*)d_in[0];
    const int* eidx   = (const int*)d_in[1];
    const int* batch  = (const int*)d_in[2];
    const float* W1   = (const float*)d_in[3];
    const float* b1   = (const float*)d_in[4];
    const float* W2   = (const float*)d_in[5];
    const float* b2   = (const float*)d_in[6];
    const float* W3   = (const float*)d_in[7];
    const float* b3   = (const float*)d_in[8];
    const float* P1   = (const float*)d_in[9];
    const float* pb1  = (const float*)d_in[10];
    const float* P2   = (const float*)d_in[11];
    const float* pb2  = (const float*)d_in[12];
    const float* ln_g = (const float*)d_in[13];
    const float* ln_b = (const float*)d_in[14];
    float* out = (float*)d_out;

    const int N = in_sizes[2];            // 50000
    const int E = in_sizes[1] / 2;        // 800000
    const int F_IN = in_sizes[0] / N;     // 128
    const int H = in_sizes[4];            // 256
    const int D = in_sizes[12];           // 768
    const int G = out_size / D;           // 1024
    const int NPAD = (N + 127) & ~127;
    const int NB = (N + 511) / 512;       // scan blocks (<=128)

    const int* src = eidx;
    const int* dst = eidx + E;

    char* ws = (char*)d_ws;
    size_t off = 0;
    auto alloc = [&](size_t bytes) -> char* {
        char* p = ws + off;
        off = (off + bytes + 255) & ~(size_t)255;
        return p;
    };
    int*   cnt      = (int*)alloc((size_t)NPAD * 4);
    float* dinv     = (float*)alloc((size_t)NPAD * 4);
    int*   row_ptr  = (int*)alloc((size_t)(N + 1) * 4);
    int*   bsum     = (int*)alloc(128 * 4);
    int*   rank     = (int*)alloc((size_t)E * 4);
    int*   csr      = (int*)alloc((size_t)E * 4);
    unsigned char* xf8  = (unsigned char*)alloc((size_t)(N + 1) * F_IN);      // x̂ fp8, +dummy
    unsigned char* h1f8 = (unsigned char*)alloc((size_t)(N + 1) * H);         // ĥ1 fp8, +dummy
    unsigned char* h2f8 = (unsigned char*)alloc((size_t)(N + 1) * H);         // ĥ2 fp8, +dummy
    unsigned short* Wt1 = (unsigned short*)alloc((size_t)F_IN * H * 2);
    unsigned short* Wt2 = (unsigned short*)alloc((size_t)H * H * 2);
    unsigned short* Wt3 = (unsigned short*)alloc((size_t)H * H * 2);
    unsigned short* Pt1 = (unsigned short*)alloc((size_t)H * H * 2);
    unsigned short* Pt2 = (unsigned short*)alloc((size_t)H * D * 2);
    unsigned short* t1  = (unsigned short*)alloc((size_t)N * F_IN * 2);       // Σ x̂ (bf16)
    unsigned short* tA  = (unsigned short*)alloc((size_t)N * H * 2);          // Σ ĥ (bf16)
    unsigned short* hh1 = (unsigned short*)alloc((size_t)N * H * 2);          // ĥ1 bf16 (residual)
    unsigned short* hh2 = (unsigned short*)alloc((size_t)N * H * 2);          // ĥ2 bf16 (residual)
    unsigned short* h3  = (unsigned short*)alloc((size_t)N * H * 2);
    unsigned short* g0b = (unsigned short*)alloc((size_t)G * H * 2);
    unsigned short* g1b = (unsigned short*)alloc((size_t)G * H * 2);
    float* g2 = (float*)alloc((size_t)G * D * 4);
    (void)ws_size; (void)n_in;

    // --- CSR build -----------------------------------------------------------
    hipMemsetAsync(cnt, 0, (size_t)NPAD * 4, stream);
    count_kernel<<<(E + 255) / 256, 256, 0, stream>>>(dst, E, cnt, rank);
    scanA<<<NB, 512, 0, stream>>>(cnt, N, bsum, dinv);
    scanC<<<NB, 512, 0, stream>>>(cnt, N, bsum, E, row_ptr);
    scatter_kernel<<<(E + 255) / 256, 256, 0, stream>>>(src, dst, E, row_ptr, rank, csr);

    // --- conversions (one launch) -------------------------------------------
    {
        int n4 = N * F_IN / 4;
        int tot = F_IN * H + 3 * H * H + H * D;
        int total = n4 + tot + 640;
        convert_all<<<(total + 255) / 256, 256, 0, stream>>>(
            x, dinv, xf8, n4, W1, W2, W3, P1, P2, Wt1, Wt2, Wt3, Pt1, Pt2, F_IN, H, D,
            xf8 + (size_t)N * F_IN, h1f8 + (size_t)N * H, h2f8 + (size_t)N * H);
    }

    // --- GCN layers (aggregate-first, ĥ-space, fp8 gathers) -----------------
    int agg_grid = (N + 3) / 4;
    int mtiles = (N + 127) / 128;

    // layer 1: t1 = x̂[i] + Σ x̂[src]; ĥ1 = di*relu(di*(t1 W1) + b1)  (+fp8)
    aggregate128<<<agg_grid, 256, 0, stream>>>(xf8, row_ptr, csr, t1, N, N);
    wgemm<128, 1, 0, 0, 1, 1><<<dim3(4, mtiles), 256, 0, stream>>>(t1, Wt1, b1, nullptr, dinv, hh1, h1f8, N, H, 1);

    // layer 2: t2 = ĥ1[i] + Σ ĥ1[src]; ĥ2 = di*(relu(di*(t2 W2)+b2) + ĥ1/di)
    aggregate256<<<agg_grid, 256, 0, stream>>>(h1f8, row_ptr, csr, tA, N, N);
    wgemm<256, 1, 1, 0, 1, 1><<<dim3(4, mtiles), 256, 0, stream>>>(tA, Wt2, b2, hh1, dinv, hh2, h2f8, N, H, 1);

    // layer 3: t3 = ĥ2[i] + Σ ĥ2[src]; h3 = relu(di*(t3 W3)+b3) + ĥ2/di
    aggregate256<<<agg_grid, 256, 0, stream>>>(h2f8, row_ptr, csr, tA, N, N);
    wgemm<256, 1, 1, 0, 2, 0><<<dim3(4, mtiles), 256, 0, stream>>>(tA, Wt3, b3, hh2, dinv, h3, nullptr, N, H, 1);

    // --- pool + MLP + LN -----------------------------------------------------
    pool_kernel<<<(G + 3) / 4, 256, 0, stream>>>(h3, batch, g0b, N, G);
    wgemm<256, 1, 0, 0, 0, 0><<<dim3(4, G / 128), 256, 0, stream>>>(g0b, Pt1, pb1, nullptr, nullptr, g1b, nullptr, G, H, 1);
    wgemm<256, 0, 0, 1, 0, 0><<<dim3(12, G / 128), 256, 0, stream>>>(g1b, Pt2, pb2, nullptr, nullptr, g2, nullptr, G, D, 1);
    ln_kernel<<<G / 4, 256, 0, stream>>>(g2, ln_g, ln_b, out, G);
}